// Round 4
// baseline (13830.846 us; speedup 1.0000x reference)
//
#include <hip/hip_runtime.h>
#include <hip/hip_bf16.h>

#define S_ 64
#define T_ 64
#define B_ 32
#define E_ 512
#define H_ 1024
#define V_ 32000
#define H3 3072
#define H2 2048
#define EH 1536

typedef unsigned short u16;
typedef unsigned int u32;
typedef __attribute__((ext_vector_type(8))) short bf16x8;
typedef __attribute__((ext_vector_type(4))) float f32x4;

#define MFMA3(ACC, AH_, AL_, BH_, BL_)                                              \
    ACC = __builtin_amdgcn_mfma_f32_16x16x32_bf16(AL_, BH_, ACC, 0, 0, 0);          \
    ACC = __builtin_amdgcn_mfma_f32_16x16x32_bf16(AH_, BL_, ACC, 0, 0, 0);          \
    ACC = __builtin_amdgcn_mfma_f32_16x16x32_bf16(AH_, BH_, ACC, 0, 0, 0);

__device__ __forceinline__ void splitf(float x, u16& h, u16& l) {
    u32 xb = __float_as_uint(x);
    u32 hb = (xb + 0x7FFFu + ((xb >> 16) & 1u)) & 0xFFFF0000u;  // RNE bf16 (as f32 bits)
    h = (u16)(hb >> 16);
    float lf = x - __uint_as_float(hb);                          // exact residual
    u32 lb = __float_as_uint(lf);
    l = (u16)((lb + 0x7FFFu + ((lb >> 16) & 1u)) >> 16);
}

__device__ __forceinline__ float bf2f(u16 v) { return __uint_as_float(((u32)v) << 16); }

__device__ __forceinline__ void load_lds16(const void* g, void* l) {
    __builtin_amdgcn_global_load_lds((const __attribute__((address_space(1))) u32*)g,
                                     (__attribute__((address_space(3))) u32*)l, 16, 0, 0);
}

// device-scope grid barrier (cg grid.sync protocol): monotone counter, no reset
__device__ __forceinline__ void grid_bar(int* cnt, int nblk, int& gen) {
    __syncthreads();
    if (threadIdx.x == 0) {
        __threadfence();
        __hip_atomic_fetch_add(cnt, 1, __ATOMIC_RELEASE, __HIP_MEMORY_SCOPE_AGENT);
        gen += nblk;
        while (__hip_atomic_load(cnt, __ATOMIC_ACQUIRE, __HIP_MEMORY_SCOPE_AGENT) < gen)
            __builtin_amdgcn_s_sleep(1);
    }
    __syncthreads();
}

// ---------------- embedding gather + split ----------------
__global__ void k_embed_src_split(const int* __restrict__ src, const float* __restrict__ emb,
                                  u16* __restrict__ hi, u16* __restrict__ lo) {
    int row = blockIdx.x;              // s*B + b
    int tok = src[row];
    int c = threadIdx.x * 4;
    float4 v = *reinterpret_cast<const float4*>(emb + (size_t)tok * E_ + c);
    ushort4 h, l;
    splitf(v.x, h.x, l.x); splitf(v.y, h.y, l.y);
    splitf(v.z, h.z, l.z); splitf(v.w, h.w, l.w);
    *reinterpret_cast<ushort4*>(hi + (size_t)row * E_ + c) = h;
    *reinterpret_cast<ushort4*>(lo + (size_t)row * E_ + c) = l;
}

__global__ void k_embed_dec_split(const int* __restrict__ src, const int* __restrict__ trg,
                                  const float* __restrict__ emb,
                                  u16* __restrict__ hi, u16* __restrict__ lo) {
    int row = blockIdx.x;              // t*B + b
    int t = row >> 5, b = row & 31;
    int tok = (t == 0) ? src[(S_ - 1) * B_ + b] : trg[(t - 1) * B_ + b];
    int c = threadIdx.x * 4;
    float4 v = *reinterpret_cast<const float4*>(emb + (size_t)tok * E_ + c);
    ushort4 h, l;
    splitf(v.x, h.x, l.x); splitf(v.y, h.y, l.y);
    splitf(v.z, h.z, l.z); splitf(v.w, h.w, l.w);
    *reinterpret_cast<ushort4*>(hi + (size_t)row * E_ + c) = h;
    *reinterpret_cast<ushort4*>(lo + (size_t)row * E_ + c) = l;
}

// ---------------- generic f32 -> bf16 hi/lo split ----------------
__global__ __launch_bounds__(256) void k_split(const float* __restrict__ in, int ld, int cols4,
                                               u16* __restrict__ hi, u16* __restrict__ lo) {
    int c4 = blockIdx.x * 256 + threadIdx.x;
    if (c4 >= cols4) return;
    size_t r = blockIdx.y;
    float4 v = *reinterpret_cast<const float4*>(in + r * ld + (size_t)c4 * 4);
    ushort4 h, l;
    splitf(v.x, h.x, l.x); splitf(v.y, h.y, l.y);
    splitf(v.z, h.z, l.z); splitf(v.w, h.w, l.w);
    size_t o = (r * cols4 + c4) * 4;
    *reinterpret_cast<ushort4*>(hi + o) = h;
    *reinterpret_cast<ushort4*>(lo + o) = l;
}

// ---------------- gate-interleaved weight split: dst row 3i+g = src row g*1024+i ----------------
__global__ void k_wsplit_perm(const float* __restrict__ src, int ld, int coff,
                              u16* __restrict__ hi, u16* __restrict__ lo) {
    int r = blockIdx.x;                // permuted row: 3i+g
    int i = r / 3, g = r - i * 3;
    const float* p = src + (size_t)(g * H_ + i) * ld + coff;
    int c = threadIdx.x * 4;
    float4 v = *reinterpret_cast<const float4*>(p + c);
    ushort4 h, l;
    splitf(v.x, h.x, l.x); splitf(v.y, h.y, l.y);
    splitf(v.z, h.z, l.z); splitf(v.w, h.w, l.w);
    *reinterpret_cast<ushort4*>(hi + (size_t)r * H_ + c) = h;
    *reinterpret_cast<ushort4*>(lo + (size_t)r * H_ + c) = l;
}

// ---------------- big split-bf16 MFMA GEMM (proven R2/R3) ----------------
__global__ __launch_bounds__(256, 2) void k_gemm_mfma3(
    const u16* __restrict__ Ah, const u16* __restrict__ Al,
    const u16* __restrict__ Bh, const u16* __restrict__ Bl,
    const float* __restrict__ bias, float* __restrict__ C,
    int ldc, int K)
{
    __shared__ u16 ls[4][128 * 32];
    const int tid = threadIdx.x;
    const int lane = tid & 63, w = tid >> 6;
    const int wr = w >> 1, wc = w & 1;
    const size_t m0 = (size_t)blockIdx.x * 128, n0 = (size_t)blockIdx.y * 128;

    const int c0 = (w * 2) * 64 + lane;
    const int r0 = c0 >> 2, kc0 = (c0 & 3) << 3;
    const size_t rstep = (size_t)16 * K;
    const u16* gAh = Ah + (m0 + r0) * K + kc0;
    const u16* gAl = Al + (m0 + r0) * K + kc0;
    const u16* gBh = Bh + (n0 + r0) * K + kc0;
    const u16* gBl = Bl + (n0 + r0) * K + kc0;
    const int lo0 = c0 * 8;

    const int frow = lane & 15, fk = (lane >> 4) << 3;
    const int offA = (wr * 64 + frow) * 32 + fk;
    const int offB = (wc * 64 + frow) * 32 + fk;

    f32x4 acc[4][4] = {};

    for (int k0 = 0; k0 < K; k0 += 32) {
        load_lds16(gAh + k0, &ls[0][lo0]);
        load_lds16(gAh + rstep + k0, &ls[0][lo0 + 512]);
        load_lds16(gAl + k0, &ls[1][lo0]);
        load_lds16(gAl + rstep + k0, &ls[1][lo0 + 512]);
        load_lds16(gBh + k0, &ls[2][lo0]);
        load_lds16(gBh + rstep + k0, &ls[2][lo0 + 512]);
        load_lds16(gBl + k0, &ls[3][lo0]);
        load_lds16(gBl + rstep + k0, &ls[3][lo0 + 512]);
        __syncthreads();

        bf16x8 fAh[4], fAl[4], fBh[4], fBl[4];
#pragma unroll
        for (int m = 0; m < 4; ++m) {
            fAh[m] = *reinterpret_cast<const bf16x8*>(&ls[0][offA + m * 512]);
            fAl[m] = *reinterpret_cast<const bf16x8*>(&ls[1][offA + m * 512]);
        }
#pragma unroll
        for (int n = 0; n < 4; ++n) {
            fBh[n] = *reinterpret_cast<const bf16x8*>(&ls[2][offB + n * 512]);
            fBl[n] = *reinterpret_cast<const bf16x8*>(&ls[3][offB + n * 512]);
        }
#pragma unroll
        for (int m = 0; m < 4; ++m)
#pragma unroll
            for (int n = 0; n < 4; ++n) {
                MFMA3(acc[m][n], fAh[m], fAl[m], fBh[n], fBl[n]);
            }
        __syncthreads();
    }

    const int crow0 = wr * 64 + ((lane >> 4) << 2);
    const int ccol0 = wc * 64 + (lane & 15);
#pragma unroll
    for (int n = 0; n < 4; ++n) {
        const size_t col = n0 + ccol0 + n * 16;
        const float bv = bias ? bias[col] : 0.f;
#pragma unroll
        for (int m = 0; m < 4; ++m)
#pragma unroll
            for (int r = 0; r < 4; ++r)
                C[(m0 + crow0 + m * 16 + r) * (size_t)ldc + col] = acc[m][n][r] + bv;
    }
}

// ================= persistent encoder: 64 GRU steps, both dirs, 1 barrier/step =================
// grid 128: dir = blk>>6, c = blk&63 -> hidden units [16c,16c+16), permuted rows [48c,48c+48)
__global__ __launch_bounds__(256) void k_enc_persist(
    const u16* __restrict__ whhf_h, const u16* __restrict__ whhf_l,
    const u16* __restrict__ whhb_h, const u16* __restrict__ whhb_l,
    const float* __restrict__ gi_f, const float* __restrict__ gi_b,
    const float* __restrict__ bhh_f, const float* __restrict__ bhh_b,
    u16* __restrict__ hfH0, u16* __restrict__ hfL0,
    u16* __restrict__ hfH1, u16* __restrict__ hfL1,
    u16* __restrict__ hbH0, u16* __restrict__ hbL0,
    u16* __restrict__ hbH1, u16* __restrict__ hbL1,
    float* __restrict__ enc, int* __restrict__ bar)
{
    __shared__ __align__(16) char smem[107008];
    u16* lH = (u16*)smem;                       // [48][1024] hi weights, XOR-swizzled
    float* ex = (float*)(smem + 98304);         // [48][33] gh exchange
    float* hloc = (float*)(smem + 104704);      // [32][16] f32 state

    const int blk = blockIdx.x, tid = threadIdx.x;
    const int lane = tid & 63, w = tid >> 6;
    const int dir = blk >> 6, c = blk & 63;
    const int i0 = c * 16;
    const size_t rowbase = (size_t)c * 48;
    const u16* WH = (dir ? whhb_h : whhf_h) + rowbase * 1024;
    const u16* WL = (dir ? whhb_l : whhf_l) + rowbase * 1024;
    const float* gi = dir ? gi_b : gi_f;
    const float* bhh = dir ? bhh_b : bhh_f;
    int gen = 0;

    for (int ch = tid; ch < 6144; ch += 256) {   // 48 rows x 128 chunks
        int r = ch >> 7, kc = (ch & 127) << 3;
        *(bf16x8*)&lH[r * 1024 + (kc ^ ((r & 7) << 3))] =
            *(const bf16x8*)&WH[(size_t)r * 1024 + kc];
    }
    for (int q = tid; q < 512; q += 256) hloc[q] = 0.f;
    __syncthreads();

    const int frow = lane & 15, fk8 = (lane >> 4) << 3;
    const int cb = lane & 15, rb0 = (lane >> 4) << 2;

    for (int t = 0; t < 64; ++t) {
        const int a = t & 1;
        const u16* rH = dir ? (a ? hbH1 : hbH0) : (a ? hfH1 : hfH0);
        const u16* rL = dir ? (a ? hbL1 : hbL0) : (a ? hfL1 : hfL0);
        u16* oH = dir ? (a ? hbH0 : hbH1) : (a ? hfH0 : hfH1);
        u16* oL = dir ? (a ? hbL0 : hbL1) : (a ? hfL0 : hfL1);
        const int s = dir ? 63 - t : t;

        if (w < 2) {                              // tiles (m0,n=w),(m1,n=w)
            f32x4 acc0 = {}, acc1 = {};
            const int lrB = w * 16 + frow;
            const int bsw = (lrB & 7) << 3;
            const u16* gBl = WL + (size_t)lrB * 1024;
#pragma unroll 4
            for (int k0 = 0; k0 < 1024; k0 += 32) {
                int kc = k0 + fk8;
                bf16x8 bH = *(const bf16x8*)&lH[lrB * 1024 + (kc ^ bsw)];
                bf16x8 bL = *(const bf16x8*)&gBl[kc];
                bf16x8 aH0 = *(const bf16x8*)&rH[frow * 1024 + kc];
                bf16x8 aL0 = *(const bf16x8*)&rL[frow * 1024 + kc];
                bf16x8 aH1 = *(const bf16x8*)&rH[(16 + frow) * 1024 + kc];
                bf16x8 aL1 = *(const bf16x8*)&rL[(16 + frow) * 1024 + kc];
                MFMA3(acc0, aH0, aL0, bH, bL);
                MFMA3(acc1, aH1, aL1, bH, bL);
            }
            int pc = w * 16 + cb;
#pragma unroll
            for (int r = 0; r < 4; ++r) {
                ex[pc * 33 + rb0 + r] = acc0[r];
                ex[pc * 33 + 16 + rb0 + r] = acc1[r];
            }
        } else {                                  // single tile (m=w-2, n=2), k-parity dual acc
            f32x4 acc0 = {}, acc1 = {};
            const int m = w - 2;
            const int lrB = 32 + frow;
            const int bsw = (lrB & 7) << 3;
            const u16* gBl = WL + (size_t)lrB * 1024;
#pragma unroll 2
            for (int k0 = 0; k0 < 1024; k0 += 64) {
                {
                    int kc = k0 + fk8;
                    bf16x8 bH = *(const bf16x8*)&lH[lrB * 1024 + (kc ^ bsw)];
                    bf16x8 bL = *(const bf16x8*)&gBl[kc];
                    bf16x8 aH = *(const bf16x8*)&rH[(m * 16 + frow) * 1024 + kc];
                    bf16x8 aL = *(const bf16x8*)&rL[(m * 16 + frow) * 1024 + kc];
                    MFMA3(acc0, aH, aL, bH, bL);
                }
                {
                    int kc = k0 + 32 + fk8;
                    bf16x8 bH = *(const bf16x8*)&lH[lrB * 1024 + (kc ^ bsw)];
                    bf16x8 bL = *(const bf16x8*)&gBl[kc];
                    bf16x8 aH = *(const bf16x8*)&rH[(m * 16 + frow) * 1024 + kc];
                    bf16x8 aL = *(const bf16x8*)&rL[(m * 16 + frow) * 1024 + kc];
                    MFMA3(acc1, aH, aL, bH, bL);
                }
            }
            f32x4 accs = acc0 + acc1;
            int pc = 32 + cb;
#pragma unroll
            for (int r = 0; r < 4; ++r)
                ex[pc * 33 + m * 16 + rb0 + r] = accs[r];
        }
        __syncthreads();

        {   // gate fusion: 256 thr = 16 units x 16 batches, q-loop covers b+16
            const int il = tid & 15, bb = tid >> 4;
            const int i = i0 + il;
#pragma unroll
            for (int q = 0; q < 2; ++q) {
                int b = bb + q * 16;
                float ghr = ex[(3 * il + 0) * 33 + b] + bhh[i];
                float ghz = ex[(3 * il + 1) * 33 + b] + bhh[H_ + i];
                float ghn = ex[(3 * il + 2) * 33 + b] + bhh[2 * H_ + i];
                size_t gio = (size_t)(s * B_ + b) * H3 + i;
                float gir = gi[gio], giz = gi[gio + H_], gin = gi[gio + 2 * H_];
                float rr = 1.f / (1.f + expf(-(gir + ghr)));
                float zz = 1.f / (1.f + expf(-(giz + ghz)));
                float nn = tanhf(gin + rr * ghn);
                float hold = hloc[b * 16 + il];
                float hnew = (1.f - zz) * nn + zz * hold;
                hloc[b * 16 + il] = hnew;
                u16 hh, hl; splitf(hnew, hh, hl);
                oH[b * 1024 + i] = hh;
                oL[b * 1024 + i] = hl;
                enc[((size_t)b * 64 + s) * H_ + i] += hnew;   // fwd@s, bwd@63-s: distinct epochs
            }
        }
        grid_bar(bar, 128, gen);
    }
}

// ================= persistent decoder: 64 steps, 3 roles, 3 barriers/step =================
// grid 224: blk<128 -> P1 (outv = h @ wcat^T), 128..191 -> P3 (gic+gates), 192..223 -> P2 (attn)
__global__ __launch_bounds__(256) void k_dec_persist(
    const u16* __restrict__ wcat_h, const u16* __restrict__ wcat_l,
    const u16* __restrict__ wdc_h, const u16* __restrict__ wdc_l,
    const float* __restrict__ gi_e, const float* __restrict__ bhh_d,
    const float* __restrict__ ep, const float* __restrict__ vvec,
    const float* __restrict__ enc,
    u16* __restrict__ hH, u16* __restrict__ hL,
    u16* __restrict__ ctxH, u16* __restrict__ ctxL,
    float* __restrict__ outv, float* __restrict__ states,
    int* __restrict__ bar)
{
    __shared__ __align__(16) char smem[131072];
    const int blk = blockIdx.x, tid = threadIdx.x;
    const int lane = tid & 63, w = tid >> 6;
    const int frow = lane & 15, fk8 = (lane >> 4) << 3;
    int gen = 0;

    if (blk < 128) {
        // ---------- P1: outv[32][4096] = h @ wcat^T, 32 rows/block ----------
        u16* lWH = (u16*)smem;
        u16* lWL = (u16*)(smem + 65536);
        const u16* gH = wcat_h + (size_t)blk * 32 * 1024;
        const u16* gL = wcat_l + (size_t)blk * 32 * 1024;
        for (int ch = tid; ch < 4096; ch += 256) {
            int r = ch >> 7, kc = (ch & 127) << 3;
            int sw = kc ^ ((r & 7) << 3);
            *(bf16x8*)&lWH[r * 1024 + sw] = *(const bf16x8*)&gH[(size_t)r * 1024 + kc];
            *(bf16x8*)&lWL[r * 1024 + sw] = *(const bf16x8*)&gL[(size_t)r * 1024 + kc];
        }
        __syncthreads();
        const int mt = w >> 1, nt = w & 1;
        const int arow = mt * 16 + frow;
        const int lrB = nt * 16 + frow;
        const int bsw = (lrB & 7) << 3;
        const int ocol = blk * 32 + nt * 16 + (lane & 15);
        const int ob0 = mt * 16 + ((lane >> 4) << 2);
        for (int t = 0; t < 64; ++t) {
            f32x4 acc0 = {}, acc1 = {};
#pragma unroll 2
            for (int k0 = 0; k0 < 1024; k0 += 64) {
                {
                    int kc = k0 + fk8;
                    bf16x8 aH = *(const bf16x8*)&hH[arow * 1024 + kc];
                    bf16x8 aL = *(const bf16x8*)&hL[arow * 1024 + kc];
                    bf16x8 bH = *(const bf16x8*)&lWH[lrB * 1024 + (kc ^ bsw)];
                    bf16x8 bL = *(const bf16x8*)&lWL[lrB * 1024 + (kc ^ bsw)];
                    MFMA3(acc0, aH, aL, bH, bL);
                }
                {
                    int kc = k0 + 32 + fk8;
                    bf16x8 aH = *(const bf16x8*)&hH[arow * 1024 + kc];
                    bf16x8 aL = *(const bf16x8*)&hL[arow * 1024 + kc];
                    bf16x8 bH = *(const bf16x8*)&lWH[lrB * 1024 + (kc ^ bsw)];
                    bf16x8 bL = *(const bf16x8*)&lWL[lrB * 1024 + (kc ^ bsw)];
                    MFMA3(acc1, aH, aL, bH, bL);
                }
            }
            f32x4 acc = acc0 + acc1;
#pragma unroll
            for (int r = 0; r < 4; ++r)
                outv[(size_t)(ob0 + r) * 4096 + ocol] = acc[r];
            grid_bar(bar, 224, gen);   // BAR1: outv ready
            grid_bar(bar, 224, gen);   // BAR2 (idle through attn)
            grid_bar(bar, 224, gen);   // BAR3 (idle through gates; h updated)
        }
    } else if (blk < 192) {
        // ---------- P3: gic = ctx @ wdc^T (48 perm rows) + GRU gates + state store ----------
        u16* lWH = (u16*)smem;                  // [48][1024] hi, swizzled; lo streamed
        float* ex = (float*)(smem + 98304);     // [48][33]
        float* hloc = (float*)(smem + 104704);  // [32][16]
        const int c3 = blk - 128;
        const int i0 = c3 * 16;
        const u16* WH = wdc_h + (size_t)c3 * 48 * 1024;
        const u16* WL = wdc_l + (size_t)c3 * 48 * 1024;
        for (int ch = tid; ch < 6144; ch += 256) {
            int r = ch >> 7, kc = (ch & 127) << 3;
            *(bf16x8*)&lWH[r * 1024 + (kc ^ ((r & 7) << 3))] =
                *(const bf16x8*)&WH[(size_t)r * 1024 + kc];
        }
#pragma unroll
        for (int q = 0; q < 2; ++q) {           // h0 = hi+lo recombine (err ~2^-18)
            int idx = tid + q * 256;
            int b = idx >> 4, il = idx & 15;
            hloc[idx] = bf2f(hH[b * 1024 + i0 + il]) + bf2f(hL[b * 1024 + i0 + il]);
        }
        __syncthreads();
        const int cb = lane & 15, rb0 = (lane >> 4) << 2;
        for (int t = 0; t < 64; ++t) {
            grid_bar(bar, 224, gen);   // BAR1
            grid_bar(bar, 224, gen);   // BAR2: ctx ready
            if (w < 2) {
                f32x4 acc0 = {}, acc1 = {};
                const int lrB = w * 16 + frow;
                const int bsw = (lrB & 7) << 3;
                const u16* gBl = WL + (size_t)lrB * 1024;
#pragma unroll 4
                for (int k0 = 0; k0 < 1024; k0 += 32) {
                    int kc = k0 + fk8;
                    bf16x8 bH = *(const bf16x8*)&lWH[lrB * 1024 + (kc ^ bsw)];
                    bf16x8 bL = *(const bf16x8*)&gBl[kc];
                    bf16x8 aH0 = *(const bf16x8*)&ctxH[frow * 1024 + kc];
                    bf16x8 aL0 = *(const bf16x8*)&ctxL[frow * 1024 + kc];
                    bf16x8 aH1 = *(const bf16x8*)&ctxH[(16 + frow) * 1024 + kc];
                    bf16x8 aL1 = *(const bf16x8*)&ctxL[(16 + frow) * 1024 + kc];
                    MFMA3(acc0, aH0, aL0, bH, bL);
                    MFMA3(acc1, aH1, aL1, bH, bL);
                }
                int pc = w * 16 + cb;
#pragma unroll
                for (int r = 0; r < 4; ++r) {
                    ex[pc * 33 + rb0 + r] = acc0[r];
                    ex[pc * 33 + 16 + rb0 + r] = acc1[r];
                }
            } else {
                f32x4 acc0 = {}, acc1 = {};
                const int m = w - 2;
                const int lrB = 32 + frow;
                const int bsw = (lrB & 7) << 3;
                const u16* gBl = WL + (size_t)lrB * 1024;
#pragma unroll 2
                for (int k0 = 0; k0 < 1024; k0 += 64) {
                    {
                        int kc = k0 + fk8;
                        bf16x8 bH = *(const bf16x8*)&lWH[lrB * 1024 + (kc ^ bsw)];
                        bf16x8 bL = *(const bf16x8*)&gBl[kc];
                        bf16x8 aH = *(const bf16x8*)&ctxH[(m * 16 + frow) * 1024 + kc];
                        bf16x8 aL = *(const bf16x8*)&ctxL[(m * 16 + frow) * 1024 + kc];
                        MFMA3(acc0, aH, aL, bH, bL);
                    }
                    {
                        int kc = k0 + 32 + fk8;
                        bf16x8 bH = *(const bf16x8*)&lWH[lrB * 1024 + (kc ^ bsw)];
                        bf16x8 bL = *(const bf16x8*)&gBl[kc];
                        bf16x8 aH = *(const bf16x8*)&ctxH[(m * 16 + frow) * 1024 + kc];
                        bf16x8 aL = *(const bf16x8*)&ctxL[(m * 16 + frow) * 1024 + kc];
                        MFMA3(acc1, aH, aL, bH, bL);
                    }
                }
                f32x4 accs = acc0 + acc1;
                int pc = 32 + cb;
#pragma unroll
                for (int r = 0; r < 4; ++r)
                    ex[pc * 33 + m * 16 + rb0 + r] = accs[r];
            }
            __syncthreads();
            {   // gates
                const int il = tid & 15, bb = tid >> 4;
                const int i = i0 + il;
#pragma unroll
                for (int q = 0; q < 2; ++q) {
                    int b = bb + q * 16;
                    size_t gv = (size_t)b * 4096 + 1024 + 3 * (size_t)i;
                    float ghr = outv[gv + 0] + bhh_d[i];
                    float ghz = outv[gv + 1] + bhh_d[H_ + i];
                    float ghn = outv[gv + 2] + bhh_d[2 * H_ + i];
                    size_t gio = (size_t)(t * B_ + b) * H3 + i;
                    float gir = gi_e[gio] + ex[(3 * il + 0) * 33 + b];
                    float giz = gi_e[gio + H_] + ex[(3 * il + 1) * 33 + b];
                    float gin = gi_e[gio + 2 * H_] + ex[(3 * il + 2) * 33 + b];
                    float rr = 1.f / (1.f + expf(-(gir + ghr)));
                    float zz = 1.f / (1.f + expf(-(giz + ghz)));
                    float nn = tanhf(gin + rr * ghn);
                    float hold = hloc[b * 16 + il];
                    float hnew = (1.f - zz) * nn + zz * hold;
                    hloc[b * 16 + il] = hnew;
                    u16 hh, hl; splitf(hnew, hh, hl);
                    hH[b * 1024 + i] = hh;
                    hL[b * 1024 + i] = hl;
                    states[((size_t)t * B_ + b) * H2 + i] = hnew;
                }
            }
            grid_bar(bar, 224, gen);   // BAR3: h ready
        }
    } else {
        // ---------- P2: attention for batch b = blk-192 ----------
        float* hv = (float*)smem;               // [1024]
        float* vs = hv + 1024;                  // [1024]
        float* al = vs + 1024;                  // [64]
        const int b = blk - 192;
        *(float4*)&vs[tid * 4] = *(const float4*)&vvec[tid * 4];
        for (int t = 0; t < 64; ++t) {
            grid_bar(bar, 224, gen);   // BAR1: outv ready
            *(float4*)&hv[tid * 4] = *(const float4*)&outv[(size_t)b * 4096 + tid * 4];
            __syncthreads();
            for (int ii = 0; ii < 16; ++ii) {
                int s = w * 16 + ii;
                const float* e = ep + ((size_t)b * 64 + s) * H_ + lane * 16;
                float a2 = 0.f;
#pragma unroll
                for (int r = 0; r < 4; ++r) {
                    float4 ev = *(const float4*)(e + r * 4);
                    int k = lane * 16 + r * 4;
                    a2 += fmaxf(ev.x + hv[k + 0], 0.f) * vs[k + 0];
                    a2 += fmaxf(ev.y + hv[k + 1], 0.f) * vs[k + 1];
                    a2 += fmaxf(ev.z + hv[k + 2], 0.f) * vs[k + 2];
                    a2 += fmaxf(ev.w + hv[k + 3], 0.f) * vs[k + 3];
                }
                for (int off = 32; off; off >>= 1) a2 += __shfl_down(a2, off);
                if (lane == 0) al[s] = a2;
            }
            __syncthreads();
            float exv = 0.f;
            if (tid < 64) {
                float m = -1e30f;
                for (int s2 = 0; s2 < 64; ++s2) m = fmaxf(m, al[s2]);
                float sum = 0.f;
                for (int s2 = 0; s2 < 64; ++s2) sum += expf(al[s2] - m);
                exv = expf(al[tid] - m) / sum;
            }
            __syncthreads();
            if (tid < 64) al[tid] = exv;
            __syncthreads();
            int j4 = tid * 4;
            float4 cacc = {0.f, 0.f, 0.f, 0.f};
            for (int s2 = 0; s2 < 64; ++s2) {
                float a = al[s2];
                float4 ev = *(const float4*)(enc + ((size_t)b * 64 + s2) * H_ + j4);
                cacc.x += a * ev.x; cacc.y += a * ev.y;
                cacc.z += a * ev.z; cacc.w += a * ev.w;
            }
            *(float4*)&states[((size_t)t * B_ + b) * H2 + H_ + j4] = cacc;
            ushort4 ch, cl;
            splitf(cacc.x, ch.x, cl.x); splitf(cacc.y, ch.y, cl.y);
            splitf(cacc.z, ch.z, cl.z); splitf(cacc.w, ch.w, cl.w);
            *(ushort4*)(ctxH + b * 1024 + j4) = ch;
            *(ushort4*)(ctxL + b * 1024 + j4) = cl;
            grid_bar(bar, 224, gen);   // BAR2: ctx ready
            grid_bar(bar, 224, gen);   // BAR3
        }
    }
}

extern "C" void kernel_launch(void* const* d_in, const int* in_sizes, int n_in,
                              void* d_out, int out_size, void* d_ws, size_t ws_size,
                              hipStream_t stream) {
    const int*   src   = (const int*)d_in[0];
    const int*   trg   = (const int*)d_in[1];
    const float* emb   = (const float*)d_in[2];
    const float* Wih_f = (const float*)d_in[3];
    const float* Whh_f = (const float*)d_in[4];
    const float* bih_f = (const float*)d_in[5];
    const float* bhh_f = (const float*)d_in[6];
    const float* Wih_b = (const float*)d_in[7];
    const float* Whh_b = (const float*)d_in[8];
    const float* bih_b = (const float*)d_in[9];
    const float* bhh_b = (const float*)d_in[10];
    const float* Wa    = (const float*)d_in[11];
    const float* ba    = (const float*)d_in[12];
    const float* vv    = (const float*)d_in[13];
    const float* Wih_d = (const float*)d_in[14];
    const float* Whh_d = (const float*)d_in[15];
    const float* bih_d = (const float*)d_in[16];
    const float* bhh_d = (const float*)d_in[17];
    const float* Wout  = (const float*)d_in[18];
    const float* bout  = (const float*)d_in[19];
    float* out = (float*)d_out;
    (void)in_sizes; (void)n_in; (void)out_size; (void)ws_size;

    float* w = (float*)d_ws;
    size_t o = 0;
    auto alloc = [&](size_t n) { float* p = w + o; o += n; return p; };
    float* gi_f = alloc((size_t)S_ * B_ * H3);       // encoder fwd gi; reused as gi_e
    float* gi_b = alloc((size_t)S_ * B_ * H3);       // encoder bwd gi; reused as states
    float* enc  = alloc((size_t)B_ * S_ * H_);
    float* ep   = alloc((size_t)B_ * S_ * H_);
    float* outv = alloc((size_t)B_ * 4096);
    float* barf = alloc(8);
    int* bar_enc = (int*)barf;
    int* bar_dec = bar_enc + 1;
    float* gi_e   = gi_f;
    float* states = gi_b;

    u16* wu = (u16*)(w + o);
    size_t ou = 0;
    auto alloc16 = [&](size_t n) { u16* p = wu + ou; ou += n; return p; };
    u16* semb_h  = alloc16((size_t)S_ * B_ * E_);  u16* semb_l  = alloc16((size_t)S_ * B_ * E_);
    u16* demb_h  = alloc16((size_t)T_ * B_ * E_);  u16* demb_l  = alloc16((size_t)T_ * B_ * E_);
    u16* wihf_h  = alloc16((size_t)H3 * E_);       u16* wihf_l  = alloc16((size_t)H3 * E_);
    u16* wihb_h  = alloc16((size_t)H3 * E_);       u16* wihb_l  = alloc16((size_t)H3 * E_);
    u16* wihd_h  = alloc16((size_t)H3 * E_);       u16* wihd_l  = alloc16((size_t)H3 * E_);
    u16* wae_h   = alloc16((size_t)H_ * H_);       u16* wae_l   = alloc16((size_t)H_ * H_);
    u16* enc_h   = alloc16((size_t)B_ * S_ * H_);  u16* enc_l   = alloc16((size_t)B_ * S_ * H_);
    u16* st_h    = alloc16((size_t)T_ * B_ * H2);  u16* st_l    = alloc16((size_t)T_ * B_ * H2);
    u16* wout_h  = alloc16((size_t)6400 * H2);     u16* wout_l  = alloc16((size_t)6400 * H2);
    u16* whhf_h  = alloc16((size_t)H3 * H_);       u16* whhf_l  = alloc16((size_t)H3 * H_);   // permuted
    u16* whhb_h  = alloc16((size_t)H3 * H_);       u16* whhb_l  = alloc16((size_t)H3 * H_);   // permuted
    u16* wihdc_h = alloc16((size_t)H3 * H_);       u16* wihdc_l = alloc16((size_t)H3 * H_);   // permuted
    u16* wcat_h  = alloc16((size_t)4096 * H_);     u16* wcat_l  = alloc16((size_t)4096 * H_); // natural+perm
    u16* hsf_h[2] = {alloc16(B_ * H_), alloc16(B_ * H_)};
    u16* hsf_l[2] = {alloc16(B_ * H_), alloc16(B_ * H_)};
    u16* hsb_h[2] = {alloc16(B_ * H_), alloc16(B_ * H_)};
    u16* hsb_l[2] = {alloc16(B_ * H_), alloc16(B_ * H_)};
    u16* ctx_h   = alloc16(B_ * H_);               u16* ctx_l   = alloc16(B_ * H_);

    // ---- init ----
    hipMemsetAsync(enc, 0, (size_t)B_ * S_ * H_ * sizeof(float), stream);
    hipMemsetAsync(bar_enc, 0, 2 * sizeof(int), stream);
    hipMemsetAsync(hsf_h[0], 0, B_ * H_ * sizeof(u16), stream);
    hipMemsetAsync(hsf_l[0], 0, B_ * H_ * sizeof(u16), stream);
    hipMemsetAsync(hsb_h[0], 0, B_ * H_ * sizeof(u16), stream);
    hipMemsetAsync(hsb_l[0], 0, B_ * H_ * sizeof(u16), stream);

    // ---- embeddings (gather + split) ----
    k_embed_src_split<<<S_ * B_, 128, 0, stream>>>(src, emb, semb_h, semb_l);
    k_embed_dec_split<<<T_ * B_, 128, 0, stream>>>(src, trg, emb, demb_h, demb_l);

    // ---- weight splits ----
    k_split<<<dim3(1, H3), 256, 0, stream>>>(Wih_f, E_, E_ / 4, wihf_h, wihf_l);
    k_split<<<dim3(1, H3), 256, 0, stream>>>(Wih_b, E_, E_ / 4, wihb_h, wihb_l);
    k_split<<<dim3(1, H3), 256, 0, stream>>>(Wih_d, EH, E_ / 4, wihd_h, wihd_l);        // emb part
    k_split<<<dim3(1, H_), 256, 0, stream>>>(Wa + H_, H2, H_ / 4, wae_h, wae_l);        // enc part
    k_split<<<dim3(1, H_), 256, 0, stream>>>(Wa, H2, H_ / 4, wcat_h, wcat_l);           // hWa rows (natural)
    k_wsplit_perm<<<H3, 256, 0, stream>>>(Whh_f, H_, 0, whhf_h, whhf_l);
    k_wsplit_perm<<<H3, 256, 0, stream>>>(Whh_b, H_, 0, whhb_h, whhb_l);
    k_wsplit_perm<<<H3, 256, 0, stream>>>(Wih_d, EH, E_, wihdc_h, wihdc_l);             // ctx part, permuted
    k_wsplit_perm<<<H3, 256, 0, stream>>>(Whh_d, H_, 0, wcat_h + (size_t)1024 * H_,
                                          wcat_l + (size_t)1024 * H_);                  // ghd rows, permuted

    // ---- encoder input projections (MFMA) ----
    k_gemm_mfma3<<<dim3(16, 24), 256, 0, stream>>>(semb_h, semb_l, wihf_h, wihf_l,
                                                   bih_f, gi_f, H3, E_);
    k_gemm_mfma3<<<dim3(16, 24), 256, 0, stream>>>(semb_h, semb_l, wihb_h, wihb_l,
                                                   bih_b, gi_b, H3, E_);

    // ---- encoder: persistent, 64 steps, 1 grid-barrier each ----
    k_enc_persist<<<128, 256, 0, stream>>>(
        whhf_h, whhf_l, whhb_h, whhb_l, gi_f, gi_b, bhh_f, bhh_b,
        hsf_h[0], hsf_l[0], hsf_h[1], hsf_l[1],
        hsb_h[0], hsb_l[0], hsb_h[1], hsb_l[1],
        enc, bar_enc);

    // ---- attention precompute ep + decoder emb projection ----
    k_split<<<dim3(1, B_ * S_), 256, 0, stream>>>(enc, H_, H_ / 4, enc_h, enc_l);
    k_gemm_mfma3<<<dim3(16, 8), 256, 0, stream>>>(enc_h, enc_l, wae_h, wae_l,
                                                  ba, ep, H_, H_);
    k_gemm_mfma3<<<dim3(16, 24), 256, 0, stream>>>(demb_h, demb_l, wihd_h, wihd_l,
                                                   bih_d, gi_e, H3, E_);

    // ---- decoder: persistent, 64 steps x {P1, attn, P3}, 3 grid-barriers each ----
    k_dec_persist<<<224, 256, 0, stream>>>(
        wcat_h, wcat_l, wihdc_h, wihdc_l, gi_e, bhh_d, ep, vv, enc,
        hsf_h[0], hsf_l[0], ctx_h, ctx_l, outv, states, bar_dec);

    // ---- output head: out = states @ Wout^T + bout, 5 passes of 6400 vocab rows ----
    k_split<<<dim3(2, T_ * B_), 256, 0, stream>>>(states, H2, H2 / 4, st_h, st_l);
    for (int p = 0; p < 5; ++p) {
        k_split<<<dim3(2, 6400), 256, 0, stream>>>(Wout + (size_t)p * 6400 * H2, H2,
                                                   H2 / 4, wout_h, wout_l);
        k_gemm_mfma3<<<dim3(16, 50), 256, 0, stream>>>(st_h, st_l, wout_h, wout_l,
                                                       bout + p * 6400,
                                                       out + (size_t)p * 6400, V_, H2);
    }
}

// Round 5
// 6964.807 us; speedup vs baseline: 1.9858x; 1.9858x over previous
//
#include <hip/hip_runtime.h>
#include <hip/hip_bf16.h>

#define S_ 64
#define T_ 64
#define B_ 32
#define E_ 512
#define H_ 1024
#define V_ 32000
#define H3 3072
#define H2 2048
#define EH 1536

typedef unsigned short u16;
typedef unsigned int u32;
typedef __attribute__((ext_vector_type(8))) short bf16x8;
typedef __attribute__((ext_vector_type(4))) float f32x4;

#define MFMA3(ACC, AH_, AL_, BH_, BL_)                                              \
    ACC = __builtin_amdgcn_mfma_f32_16x16x32_bf16(AL_, BH_, ACC, 0, 0, 0);          \
    ACC = __builtin_amdgcn_mfma_f32_16x16x32_bf16(AH_, BL_, ACC, 0, 0, 0);          \
    ACC = __builtin_amdgcn_mfma_f32_16x16x32_bf16(AH_, BH_, ACC, 0, 0, 0);

__device__ __forceinline__ void splitf(float x, u16& h, u16& l) {
    u32 xb = __float_as_uint(x);
    u32 hb = (xb + 0x7FFFu + ((xb >> 16) & 1u)) & 0xFFFF0000u;  // RNE bf16 (as f32 bits)
    h = (u16)(hb >> 16);
    float lf = x - __uint_as_float(hb);                          // exact residual
    u32 lb = __float_as_uint(lf);
    l = (u16)((lb + 0x7FFFu + ((lb >> 16) & 1u)) >> 16);
}

__device__ __forceinline__ float bf2f(u16 v) { return __uint_as_float(((u32)v) << 16); }

__device__ __forceinline__ void load_lds16(const void* g, void* l) {
    __builtin_amdgcn_global_load_lds((const __attribute__((address_space(1))) u32*)g,
                                     (__attribute__((address_space(3))) u32*)l, 16, 0, 0);
}

// device-scope grid barrier, FIXED (R4 post-mortem): RELEASE only on arrive,
// RELAXED polling (no per-poll cache invalidate!), single acquire fence on exit.
__device__ __forceinline__ void grid_bar(int* cnt, int nblk, int& gen) {
    __syncthreads();
    if (threadIdx.x == 0) {
        gen += nblk;
        __hip_atomic_fetch_add(cnt, 1, __ATOMIC_RELEASE, __HIP_MEMORY_SCOPE_AGENT);
        while (__hip_atomic_load(cnt, __ATOMIC_RELAXED, __HIP_MEMORY_SCOPE_AGENT) < gen)
            __builtin_amdgcn_s_sleep(8);
        __builtin_amdgcn_fence(__ATOMIC_ACQUIRE, "agent");
    }
    __syncthreads();
}

// ---------------- embedding gather + split ----------------
__global__ void k_embed_src_split(const int* __restrict__ src, const float* __restrict__ emb,
                                  u16* __restrict__ hi, u16* __restrict__ lo) {
    int row = blockIdx.x;              // s*B + b
    int tok = src[row];
    int c = threadIdx.x * 4;
    float4 v = *reinterpret_cast<const float4*>(emb + (size_t)tok * E_ + c);
    ushort4 h, l;
    splitf(v.x, h.x, l.x); splitf(v.y, h.y, l.y);
    splitf(v.z, h.z, l.z); splitf(v.w, h.w, l.w);
    *reinterpret_cast<ushort4*>(hi + (size_t)row * E_ + c) = h;
    *reinterpret_cast<ushort4*>(lo + (size_t)row * E_ + c) = l;
}

__global__ void k_embed_dec_split(const int* __restrict__ src, const int* __restrict__ trg,
                                  const float* __restrict__ emb,
                                  u16* __restrict__ hi, u16* __restrict__ lo) {
    int row = blockIdx.x;              // t*B + b
    int t = row >> 5, b = row & 31;
    int tok = (t == 0) ? src[(S_ - 1) * B_ + b] : trg[(t - 1) * B_ + b];
    int c = threadIdx.x * 4;
    float4 v = *reinterpret_cast<const float4*>(emb + (size_t)tok * E_ + c);
    ushort4 h, l;
    splitf(v.x, h.x, l.x); splitf(v.y, h.y, l.y);
    splitf(v.z, h.z, l.z); splitf(v.w, h.w, l.w);
    *reinterpret_cast<ushort4*>(hi + (size_t)row * E_ + c) = h;
    *reinterpret_cast<ushort4*>(lo + (size_t)row * E_ + c) = l;
}

// ---------------- generic f32 -> bf16 hi/lo split ----------------
__global__ __launch_bounds__(256) void k_split(const float* __restrict__ in, int ld, int cols4,
                                               u16* __restrict__ hi, u16* __restrict__ lo) {
    int c4 = blockIdx.x * 256 + threadIdx.x;
    if (c4 >= cols4) return;
    size_t r = blockIdx.y;
    float4 v = *reinterpret_cast<const float4*>(in + r * ld + (size_t)c4 * 4);
    ushort4 h, l;
    splitf(v.x, h.x, l.x); splitf(v.y, h.y, l.y);
    splitf(v.z, h.z, l.z); splitf(v.w, h.w, l.w);
    size_t o = (r * cols4 + c4) * 4;
    *reinterpret_cast<ushort4*>(hi + o) = h;
    *reinterpret_cast<ushort4*>(lo + o) = l;
}

// ---------------- gate-interleaved weight split: dst row 3i+g = src row g*1024+i ----------------
__global__ void k_wsplit_perm(const float* __restrict__ src, int ld, int coff,
                              u16* __restrict__ hi, u16* __restrict__ lo) {
    int r = blockIdx.x;                // permuted row: 3i+g
    int i = r / 3, g = r - i * 3;
    const float* p = src + (size_t)(g * H_ + i) * ld + coff;
    int c = threadIdx.x * 4;
    float4 v = *reinterpret_cast<const float4*>(p + c);
    ushort4 h, l;
    splitf(v.x, h.x, l.x); splitf(v.y, h.y, l.y);
    splitf(v.z, h.z, l.z); splitf(v.w, h.w, l.w);
    *reinterpret_cast<ushort4*>(hi + (size_t)r * H_ + c) = h;
    *reinterpret_cast<ushort4*>(lo + (size_t)r * H_ + c) = l;
}

// ---------------- big split-bf16 MFMA GEMM (proven R2/R3) ----------------
__global__ __launch_bounds__(256, 2) void k_gemm_mfma3(
    const u16* __restrict__ Ah, const u16* __restrict__ Al,
    const u16* __restrict__ Bh, const u16* __restrict__ Bl,
    const float* __restrict__ bias, float* __restrict__ C,
    int ldc, int K)
{
    __shared__ u16 ls[4][128 * 32];
    const int tid = threadIdx.x;
    const int lane = tid & 63, w = tid >> 6;
    const int wr = w >> 1, wc = w & 1;
    const size_t m0 = (size_t)blockIdx.x * 128, n0 = (size_t)blockIdx.y * 128;

    const int c0 = (w * 2) * 64 + lane;
    const int r0 = c0 >> 2, kc0 = (c0 & 3) << 3;
    const size_t rstep = (size_t)16 * K;
    const u16* gAh = Ah + (m0 + r0) * K + kc0;
    const u16* gAl = Al + (m0 + r0) * K + kc0;
    const u16* gBh = Bh + (n0 + r0) * K + kc0;
    const u16* gBl = Bl + (n0 + r0) * K + kc0;
    const int lo0 = c0 * 8;

    const int frow = lane & 15, fk = (lane >> 4) << 3;
    const int offA = (wr * 64 + frow) * 32 + fk;
    const int offB = (wc * 64 + frow) * 32 + fk;

    f32x4 acc[4][4] = {};

    for (int k0 = 0; k0 < K; k0 += 32) {
        load_lds16(gAh + k0, &ls[0][lo0]);
        load_lds16(gAh + rstep + k0, &ls[0][lo0 + 512]);
        load_lds16(gAl + k0, &ls[1][lo0]);
        load_lds16(gAl + rstep + k0, &ls[1][lo0 + 512]);
        load_lds16(gBh + k0, &ls[2][lo0]);
        load_lds16(gBh + rstep + k0, &ls[2][lo0 + 512]);
        load_lds16(gBl + k0, &ls[3][lo0]);
        load_lds16(gBl + rstep + k0, &ls[3][lo0 + 512]);
        __syncthreads();

        bf16x8 fAh[4], fAl[4], fBh[4], fBl[4];
#pragma unroll
        for (int m = 0; m < 4; ++m) {
            fAh[m] = *reinterpret_cast<const bf16x8*>(&ls[0][offA + m * 512]);
            fAl[m] = *reinterpret_cast<const bf16x8*>(&ls[1][offA + m * 512]);
        }
#pragma unroll
        for (int n = 0; n < 4; ++n) {
            fBh[n] = *reinterpret_cast<const bf16x8*>(&ls[2][offB + n * 512]);
            fBl[n] = *reinterpret_cast<const bf16x8*>(&ls[3][offB + n * 512]);
        }
#pragma unroll
        for (int m = 0; m < 4; ++m)
#pragma unroll
            for (int n = 0; n < 4; ++n) {
                MFMA3(acc[m][n], fAh[m], fAl[m], fBh[n], fBl[n]);
            }
        __syncthreads();
    }

    const int crow0 = wr * 64 + ((lane >> 4) << 2);
    const int ccol0 = wc * 64 + (lane & 15);
#pragma unroll
    for (int n = 0; n < 4; ++n) {
        const size_t col = n0 + ccol0 + n * 16;
        const float bv = bias ? bias[col] : 0.f;
#pragma unroll
        for (int m = 0; m < 4; ++m)
#pragma unroll
            for (int r = 0; r < 4; ++r)
                C[(m0 + crow0 + m * 16 + r) * (size_t)ldc + col] = acc[m][n][r] + bv;
    }
}

// ================= persistent encoder: 64 GRU steps, both dirs, 1 barrier/step =================
// grid 128: dir = blk>>6, c = blk&63 -> hidden units [16c,16c+16), permuted rows [48c,48c+48)
__global__ __launch_bounds__(256) void k_enc_persist(
    const u16* __restrict__ whhf_h, const u16* __restrict__ whhf_l,
    const u16* __restrict__ whhb_h, const u16* __restrict__ whhb_l,
    const float* __restrict__ gi_f, const float* __restrict__ gi_b,
    const float* __restrict__ bhh_f, const float* __restrict__ bhh_b,
    u16* __restrict__ hfH0, u16* __restrict__ hfL0,
    u16* __restrict__ hfH1, u16* __restrict__ hfL1,
    u16* __restrict__ hbH0, u16* __restrict__ hbL0,
    u16* __restrict__ hbH1, u16* __restrict__ hbL1,
    float* __restrict__ enc, int* __restrict__ bar)
{
    __shared__ __align__(16) char smem[107008];
    u16* lH = (u16*)smem;                       // [48][1024] hi weights, XOR-swizzled
    float* ex = (float*)(smem + 98304);         // [48][33] gh exchange
    float* hloc = (float*)(smem + 104704);      // [32][16] f32 state

    const int blk = blockIdx.x, tid = threadIdx.x;
    const int lane = tid & 63, w = tid >> 6;
    const int dir = blk >> 6, c = blk & 63;
    const int i0 = c * 16;
    const size_t rowbase = (size_t)c * 48;
    const u16* WH = (dir ? whhb_h : whhf_h) + rowbase * 1024;
    const u16* WL = (dir ? whhb_l : whhf_l) + rowbase * 1024;
    const float* gi = dir ? gi_b : gi_f;
    const float* bhh = dir ? bhh_b : bhh_f;
    int gen = 0;

    for (int ch = tid; ch < 6144; ch += 256) {   // 48 rows x 128 chunks
        int r = ch >> 7, kc = (ch & 127) << 3;
        *(bf16x8*)&lH[r * 1024 + (kc ^ ((r & 7) << 3))] =
            *(const bf16x8*)&WH[(size_t)r * 1024 + kc];
    }
    for (int q = tid; q < 512; q += 256) hloc[q] = 0.f;
    __syncthreads();

    const int frow = lane & 15, fk8 = (lane >> 4) << 3;
    const int cb = lane & 15, rb0 = (lane >> 4) << 2;

    for (int t = 0; t < 64; ++t) {
        const int a = t & 1;
        const u16* rH = dir ? (a ? hbH1 : hbH0) : (a ? hfH1 : hfH0);
        const u16* rL = dir ? (a ? hbL1 : hbL0) : (a ? hfL1 : hfL0);
        u16* oH = dir ? (a ? hbH0 : hbH1) : (a ? hfH0 : hfH1);
        u16* oL = dir ? (a ? hbL0 : hbL1) : (a ? hfL0 : hfL1);
        const int s = dir ? 63 - t : t;

        if (w < 2) {                              // tiles (m0,n=w),(m1,n=w)
            f32x4 acc0 = {}, acc1 = {};
            const int lrB = w * 16 + frow;
            const int bsw = (lrB & 7) << 3;
            const u16* gBl = WL + (size_t)lrB * 1024;
#pragma unroll 4
            for (int k0 = 0; k0 < 1024; k0 += 32) {
                int kc = k0 + fk8;
                bf16x8 bH = *(const bf16x8*)&lH[lrB * 1024 + (kc ^ bsw)];
                bf16x8 bL = *(const bf16x8*)&gBl[kc];
                bf16x8 aH0 = *(const bf16x8*)&rH[frow * 1024 + kc];
                bf16x8 aL0 = *(const bf16x8*)&rL[frow * 1024 + kc];
                bf16x8 aH1 = *(const bf16x8*)&rH[(16 + frow) * 1024 + kc];
                bf16x8 aL1 = *(const bf16x8*)&rL[(16 + frow) * 1024 + kc];
                MFMA3(acc0, aH0, aL0, bH, bL);
                MFMA3(acc1, aH1, aL1, bH, bL);
            }
            int pc = w * 16 + cb;
#pragma unroll
            for (int r = 0; r < 4; ++r) {
                ex[pc * 33 + rb0 + r] = acc0[r];
                ex[pc * 33 + 16 + rb0 + r] = acc1[r];
            }
        } else {                                  // single tile (m=w-2, n=2), k-parity dual acc
            f32x4 acc0 = {}, acc1 = {};
            const int m = w - 2;
            const int lrB = 32 + frow;
            const int bsw = (lrB & 7) << 3;
            const u16* gBl = WL + (size_t)lrB * 1024;
#pragma unroll 2
            for (int k0 = 0; k0 < 1024; k0 += 64) {
                {
                    int kc = k0 + fk8;
                    bf16x8 bH = *(const bf16x8*)&lH[lrB * 1024 + (kc ^ bsw)];
                    bf16x8 bL = *(const bf16x8*)&gBl[kc];
                    bf16x8 aH = *(const bf16x8*)&rH[(m * 16 + frow) * 1024 + kc];
                    bf16x8 aL = *(const bf16x8*)&rL[(m * 16 + frow) * 1024 + kc];
                    MFMA3(acc0, aH, aL, bH, bL);
                }
                {
                    int kc = k0 + 32 + fk8;
                    bf16x8 bH = *(const bf16x8*)&lH[lrB * 1024 + (kc ^ bsw)];
                    bf16x8 bL = *(const bf16x8*)&gBl[kc];
                    bf16x8 aH = *(const bf16x8*)&rH[(m * 16 + frow) * 1024 + kc];
                    bf16x8 aL = *(const bf16x8*)&rL[(m * 16 + frow) * 1024 + kc];
                    MFMA3(acc1, aH, aL, bH, bL);
                }
            }
            f32x4 accs = acc0 + acc1;
            int pc = 32 + cb;
#pragma unroll
            for (int r = 0; r < 4; ++r)
                ex[pc * 33 + m * 16 + rb0 + r] = accs[r];
        }
        __syncthreads();

        {   // gate fusion: 256 thr = 16 units x 16 batches, q-loop covers b+16
            const int il = tid & 15, bb = tid >> 4;
            const int i = i0 + il;
#pragma unroll
            for (int q = 0; q < 2; ++q) {
                int b = bb + q * 16;
                float ghr = ex[(3 * il + 0) * 33 + b] + bhh[i];
                float ghz = ex[(3 * il + 1) * 33 + b] + bhh[H_ + i];
                float ghn = ex[(3 * il + 2) * 33 + b] + bhh[2 * H_ + i];
                size_t gio = (size_t)(s * B_ + b) * H3 + i;
                float gir = gi[gio], giz = gi[gio + H_], gin = gi[gio + 2 * H_];
                float rr = 1.f / (1.f + expf(-(gir + ghr)));
                float zz = 1.f / (1.f + expf(-(giz + ghz)));
                float nn = tanhf(gin + rr * ghn);
                float hold = hloc[b * 16 + il];
                float hnew = (1.f - zz) * nn + zz * hold;
                hloc[b * 16 + il] = hnew;
                u16 hh, hl; splitf(hnew, hh, hl);
                oH[b * 1024 + i] = hh;
                oL[b * 1024 + i] = hl;
                enc[((size_t)b * 64 + s) * H_ + i] += hnew;   // fwd@s, bwd@63-s: distinct epochs
            }
        }
        grid_bar(bar, 128, gen);
    }
}

// ================= persistent decoder: 64 steps, 3 roles, 3 barriers/step =================
// grid 224: blk<128 -> P1 (outv = h @ wcat^T), 128..191 -> P3 (gic+gates), 192..223 -> P2 (attn)
__global__ __launch_bounds__(256) void k_dec_persist(
    const u16* __restrict__ wcat_h, const u16* __restrict__ wcat_l,
    const u16* __restrict__ wdc_h, const u16* __restrict__ wdc_l,
    const float* __restrict__ gi_e, const float* __restrict__ bhh_d,
    const float* __restrict__ ep, const float* __restrict__ vvec,
    const float* __restrict__ enc,
    u16* __restrict__ hH, u16* __restrict__ hL,
    u16* __restrict__ ctxH, u16* __restrict__ ctxL,
    float* __restrict__ outv, float* __restrict__ states,
    int* __restrict__ bar)
{
    __shared__ __align__(16) char smem[131072];
    const int blk = blockIdx.x, tid = threadIdx.x;
    const int lane = tid & 63, w = tid >> 6;
    const int frow = lane & 15, fk8 = (lane >> 4) << 3;
    int gen = 0;

    if (blk < 128) {
        // ---------- P1: outv[32][4096] = h @ wcat^T, 32 rows/block ----------
        u16* lWH = (u16*)smem;
        u16* lWL = (u16*)(smem + 65536);
        const u16* gH = wcat_h + (size_t)blk * 32 * 1024;
        const u16* gL = wcat_l + (size_t)blk * 32 * 1024;
        for (int ch = tid; ch < 4096; ch += 256) {
            int r = ch >> 7, kc = (ch & 127) << 3;
            int sw = kc ^ ((r & 7) << 3);
            *(bf16x8*)&lWH[r * 1024 + sw] = *(const bf16x8*)&gH[(size_t)r * 1024 + kc];
            *(bf16x8*)&lWL[r * 1024 + sw] = *(const bf16x8*)&gL[(size_t)r * 1024 + kc];
        }
        __syncthreads();
        const int mt = w >> 1, nt = w & 1;
        const int arow = mt * 16 + frow;
        const int lrB = nt * 16 + frow;
        const int bsw = (lrB & 7) << 3;
        const int ocol = blk * 32 + nt * 16 + (lane & 15);
        const int ob0 = mt * 16 + ((lane >> 4) << 2);
        for (int t = 0; t < 64; ++t) {
            f32x4 acc0 = {}, acc1 = {};
#pragma unroll 2
            for (int k0 = 0; k0 < 1024; k0 += 64) {
                {
                    int kc = k0 + fk8;
                    bf16x8 aH = *(const bf16x8*)&hH[arow * 1024 + kc];
                    bf16x8 aL = *(const bf16x8*)&hL[arow * 1024 + kc];
                    bf16x8 bH = *(const bf16x8*)&lWH[lrB * 1024 + (kc ^ bsw)];
                    bf16x8 bL = *(const bf16x8*)&lWL[lrB * 1024 + (kc ^ bsw)];
                    MFMA3(acc0, aH, aL, bH, bL);
                }
                {
                    int kc = k0 + 32 + fk8;
                    bf16x8 aH = *(const bf16x8*)&hH[arow * 1024 + kc];
                    bf16x8 aL = *(const bf16x8*)&hL[arow * 1024 + kc];
                    bf16x8 bH = *(const bf16x8*)&lWH[lrB * 1024 + (kc ^ bsw)];
                    bf16x8 bL = *(const bf16x8*)&lWL[lrB * 1024 + (kc ^ bsw)];
                    MFMA3(acc1, aH, aL, bH, bL);
                }
            }
            f32x4 acc = acc0 + acc1;
#pragma unroll
            for (int r = 0; r < 4; ++r)
                outv[(size_t)(ob0 + r) * 4096 + ocol] = acc[r];
            grid_bar(bar, 224, gen);   // BAR1: outv ready
            grid_bar(bar, 224, gen);   // BAR2 (idle through attn)
            grid_bar(bar, 224, gen);   // BAR3 (idle through gates; h updated)
        }
    } else if (blk < 192) {
        // ---------- P3: gic = ctx @ wdc^T (48 perm rows) + GRU gates + state store ----------
        u16* lWH = (u16*)smem;                  // [48][1024] hi, swizzled; lo streamed
        float* ex = (float*)(smem + 98304);     // [48][33]
        float* hloc = (float*)(smem + 104704);  // [32][16]
        const int c3 = blk - 128;
        const int i0 = c3 * 16;
        const u16* WH = wdc_h + (size_t)c3 * 48 * 1024;
        const u16* WL = wdc_l + (size_t)c3 * 48 * 1024;
        for (int ch = tid; ch < 6144; ch += 256) {
            int r = ch >> 7, kc = (ch & 127) << 3;
            *(bf16x8*)&lWH[r * 1024 + (kc ^ ((r & 7) << 3))] =
                *(const bf16x8*)&WH[(size_t)r * 1024 + kc];
        }
#pragma unroll
        for (int q = 0; q < 2; ++q) {           // h0 = hi+lo recombine (err ~2^-18)
            int idx = tid + q * 256;
            int b = idx >> 4, il = idx & 15;
            hloc[idx] = bf2f(hH[b * 1024 + i0 + il]) + bf2f(hL[b * 1024 + i0 + il]);
        }
        __syncthreads();
        const int cb = lane & 15, rb0 = (lane >> 4) << 2;
        for (int t = 0; t < 64; ++t) {
            grid_bar(bar, 224, gen);   // BAR1
            grid_bar(bar, 224, gen);   // BAR2: ctx ready
            if (w < 2) {
                f32x4 acc0 = {}, acc1 = {};
                const int lrB = w * 16 + frow;
                const int bsw = (lrB & 7) << 3;
                const u16* gBl = WL + (size_t)lrB * 1024;
#pragma unroll 4
                for (int k0 = 0; k0 < 1024; k0 += 32) {
                    int kc = k0 + fk8;
                    bf16x8 bH = *(const bf16x8*)&lWH[lrB * 1024 + (kc ^ bsw)];
                    bf16x8 bL = *(const bf16x8*)&gBl[kc];
                    bf16x8 aH0 = *(const bf16x8*)&ctxH[frow * 1024 + kc];
                    bf16x8 aL0 = *(const bf16x8*)&ctxL[frow * 1024 + kc];
                    bf16x8 aH1 = *(const bf16x8*)&ctxH[(16 + frow) * 1024 + kc];
                    bf16x8 aL1 = *(const bf16x8*)&ctxL[(16 + frow) * 1024 + kc];
                    MFMA3(acc0, aH0, aL0, bH, bL);
                    MFMA3(acc1, aH1, aL1, bH, bL);
                }
                int pc = w * 16 + cb;
#pragma unroll
                for (int r = 0; r < 4; ++r) {
                    ex[pc * 33 + rb0 + r] = acc0[r];
                    ex[pc * 33 + 16 + rb0 + r] = acc1[r];
                }
            } else {
                f32x4 acc0 = {}, acc1 = {};
                const int m = w - 2;
                const int lrB = 32 + frow;
                const int bsw = (lrB & 7) << 3;
                const u16* gBl = WL + (size_t)lrB * 1024;
#pragma unroll 2
                for (int k0 = 0; k0 < 1024; k0 += 64) {
                    {
                        int kc = k0 + fk8;
                        bf16x8 bH = *(const bf16x8*)&lWH[lrB * 1024 + (kc ^ bsw)];
                        bf16x8 bL = *(const bf16x8*)&gBl[kc];
                        bf16x8 aH = *(const bf16x8*)&ctxH[(m * 16 + frow) * 1024 + kc];
                        bf16x8 aL = *(const bf16x8*)&ctxL[(m * 16 + frow) * 1024 + kc];
                        MFMA3(acc0, aH, aL, bH, bL);
                    }
                    {
                        int kc = k0 + 32 + fk8;
                        bf16x8 bH = *(const bf16x8*)&lWH[lrB * 1024 + (kc ^ bsw)];
                        bf16x8 bL = *(const bf16x8*)&gBl[kc];
                        bf16x8 aH = *(const bf16x8*)&ctxH[(m * 16 + frow) * 1024 + kc];
                        bf16x8 aL = *(const bf16x8*)&ctxL[(m * 16 + frow) * 1024 + kc];
                        MFMA3(acc1, aH, aL, bH, bL);
                    }
                }
                f32x4 accs = acc0 + acc1;
                int pc = 32 + cb;
#pragma unroll
                for (int r = 0; r < 4; ++r)
                    ex[pc * 33 + m * 16 + rb0 + r] = accs[r];
            }
            __syncthreads();
            {   // gates
                const int il = tid & 15, bb = tid >> 4;
                const int i = i0 + il;
#pragma unroll
                for (int q = 0; q < 2; ++q) {
                    int b = bb + q * 16;
                    size_t gv = (size_t)b * 4096 + 1024 + 3 * (size_t)i;
                    float ghr = outv[gv + 0] + bhh_d[i];
                    float ghz = outv[gv + 1] + bhh_d[H_ + i];
                    float ghn = outv[gv + 2] + bhh_d[2 * H_ + i];
                    size_t gio = (size_t)(t * B_ + b) * H3 + i;
                    float gir = gi_e[gio] + ex[(3 * il + 0) * 33 + b];
                    float giz = gi_e[gio + H_] + ex[(3 * il + 1) * 33 + b];
                    float gin = gi_e[gio + 2 * H_] + ex[(3 * il + 2) * 33 + b];
                    float rr = 1.f / (1.f + expf(-(gir + ghr)));
                    float zz = 1.f / (1.f + expf(-(giz + ghz)));
                    float nn = tanhf(gin + rr * ghn);
                    float hold = hloc[b * 16 + il];
                    float hnew = (1.f - zz) * nn + zz * hold;
                    hloc[b * 16 + il] = hnew;
                    u16 hh, hl; splitf(hnew, hh, hl);
                    hH[b * 1024 + i] = hh;
                    hL[b * 1024 + i] = hl;
                    states[((size_t)t * B_ + b) * H2 + i] = hnew;
                }
            }
            grid_bar(bar, 224, gen);   // BAR3: h ready
        }
    } else {
        // ---------- P2: attention for batch b = blk-192 ----------
        float* hv = (float*)smem;               // [1024]
        float* vs = hv + 1024;                  // [1024]
        float* al = vs + 1024;                  // [64]
        const int b = blk - 192;
        *(float4*)&vs[tid * 4] = *(const float4*)&vvec[tid * 4];
        for (int t = 0; t < 64; ++t) {
            grid_bar(bar, 224, gen);   // BAR1: outv ready
            *(float4*)&hv[tid * 4] = *(const float4*)&outv[(size_t)b * 4096 + tid * 4];
            __syncthreads();
            for (int ii = 0; ii < 16; ++ii) {
                int s = w * 16 + ii;
                const float* e = ep + ((size_t)b * 64 + s) * H_ + lane * 16;
                float a2 = 0.f;
#pragma unroll
                for (int r = 0; r < 4; ++r) {
                    float4 ev = *(const float4*)(e + r * 4);
                    int k = lane * 16 + r * 4;
                    a2 += fmaxf(ev.x + hv[k + 0], 0.f) * vs[k + 0];
                    a2 += fmaxf(ev.y + hv[k + 1], 0.f) * vs[k + 1];
                    a2 += fmaxf(ev.z + hv[k + 2], 0.f) * vs[k + 2];
                    a2 += fmaxf(ev.w + hv[k + 3], 0.f) * vs[k + 3];
                }
                for (int off = 32; off; off >>= 1) a2 += __shfl_down(a2, off);
                if (lane == 0) al[s] = a2;
            }
            __syncthreads();
            float exv = 0.f;
            if (tid < 64) {
                float m = -1e30f;
                for (int s2 = 0; s2 < 64; ++s2) m = fmaxf(m, al[s2]);
                float sum = 0.f;
                for (int s2 = 0; s2 < 64; ++s2) sum += expf(al[s2] - m);
                exv = expf(al[tid] - m) / sum;
            }
            __syncthreads();
            if (tid < 64) al[tid] = exv;
            __syncthreads();
            int j4 = tid * 4;
            float4 cacc = {0.f, 0.f, 0.f, 0.f};
            for (int s2 = 0; s2 < 64; ++s2) {
                float a = al[s2];
                float4 ev = *(const float4*)(enc + ((size_t)b * 64 + s2) * H_ + j4);
                cacc.x += a * ev.x; cacc.y += a * ev.y;
                cacc.z += a * ev.z; cacc.w += a * ev.w;
            }
            *(float4*)&states[((size_t)t * B_ + b) * H2 + H_ + j4] = cacc;
            ushort4 ch, cl;
            splitf(cacc.x, ch.x, cl.x); splitf(cacc.y, ch.y, cl.y);
            splitf(cacc.z, ch.z, cl.z); splitf(cacc.w, ch.w, cl.w);
            *(ushort4*)(ctxH + b * 1024 + j4) = ch;
            *(ushort4*)(ctxL + b * 1024 + j4) = cl;
            grid_bar(bar, 224, gen);   // BAR2: ctx ready
            grid_bar(bar, 224, gen);   // BAR3
        }
    }
}

extern "C" void kernel_launch(void* const* d_in, const int* in_sizes, int n_in,
                              void* d_out, int out_size, void* d_ws, size_t ws_size,
                              hipStream_t stream) {
    const int*   src   = (const int*)d_in[0];
    const int*   trg   = (const int*)d_in[1];
    const float* emb   = (const float*)d_in[2];
    const float* Wih_f = (const float*)d_in[3];
    const float* Whh_f = (const float*)d_in[4];
    const float* bih_f = (const float*)d_in[5];
    const float* bhh_f = (const float*)d_in[6];
    const float* Wih_b = (const float*)d_in[7];
    const float* Whh_b = (const float*)d_in[8];
    const float* bih_b = (const float*)d_in[9];
    const float* bhh_b = (const float*)d_in[10];
    const float* Wa    = (const float*)d_in[11];
    const float* ba    = (const float*)d_in[12];
    const float* vv    = (const float*)d_in[13];
    const float* Wih_d = (const float*)d_in[14];
    const float* Whh_d = (const float*)d_in[15];
    const float* bih_d = (const float*)d_in[16];
    const float* bhh_d = (const float*)d_in[17];
    const float* Wout  = (const float*)d_in[18];
    const float* bout  = (const float*)d_in[19];
    float* out = (float*)d_out;
    (void)in_sizes; (void)n_in; (void)out_size; (void)ws_size;

    float* w = (float*)d_ws;
    size_t o = 0;
    auto alloc = [&](size_t n) { float* p = w + o; o += n; return p; };
    float* gi_f = alloc((size_t)S_ * B_ * H3);       // encoder fwd gi; reused as gi_e
    float* gi_b = alloc((size_t)S_ * B_ * H3);       // encoder bwd gi; reused as states
    float* enc  = alloc((size_t)B_ * S_ * H_);
    float* ep   = alloc((size_t)B_ * S_ * H_);
    float* outv = alloc((size_t)B_ * 4096);
    float* barf = alloc(64);                          // 2 counters, separate cachelines
    int* bar_enc = (int*)barf;
    int* bar_dec = (int*)(barf + 32);
    float* gi_e   = gi_f;
    float* states = gi_b;

    u16* wu = (u16*)(w + o);
    size_t ou = 0;
    auto alloc16 = [&](size_t n) { u16* p = wu + ou; ou += n; return p; };
    u16* semb_h  = alloc16((size_t)S_ * B_ * E_);  u16* semb_l  = alloc16((size_t)S_ * B_ * E_);
    u16* demb_h  = alloc16((size_t)T_ * B_ * E_);  u16* demb_l  = alloc16((size_t)T_ * B_ * E_);
    u16* wihf_h  = alloc16((size_t)H3 * E_);       u16* wihf_l  = alloc16((size_t)H3 * E_);
    u16* wihb_h  = alloc16((size_t)H3 * E_);       u16* wihb_l  = alloc16((size_t)H3 * E_);
    u16* wihd_h  = alloc16((size_t)H3 * E_);       u16* wihd_l  = alloc16((size_t)H3 * E_);
    u16* wae_h   = alloc16((size_t)H_ * H_);       u16* wae_l   = alloc16((size_t)H_ * H_);
    u16* enc_h   = alloc16((size_t)B_ * S_ * H_);  u16* enc_l   = alloc16((size_t)B_ * S_ * H_);
    u16* st_h    = alloc16((size_t)T_ * B_ * H2);  u16* st_l    = alloc16((size_t)T_ * B_ * H2);
    u16* wout_h  = alloc16((size_t)6400 * H2);     u16* wout_l  = alloc16((size_t)6400 * H2);
    u16* whhf_h  = alloc16((size_t)H3 * H_);       u16* whhf_l  = alloc16((size_t)H3 * H_);   // permuted
    u16* whhb_h  = alloc16((size_t)H3 * H_);       u16* whhb_l  = alloc16((size_t)H3 * H_);   // permuted
    u16* wihdc_h = alloc16((size_t)H3 * H_);       u16* wihdc_l = alloc16((size_t)H3 * H_);   // permuted
    u16* wcat_h  = alloc16((size_t)4096 * H_);     u16* wcat_l  = alloc16((size_t)4096 * H_); // natural+perm
    u16* hsf_h[2] = {alloc16(B_ * H_), alloc16(B_ * H_)};
    u16* hsf_l[2] = {alloc16(B_ * H_), alloc16(B_ * H_)};
    u16* hsb_h[2] = {alloc16(B_ * H_), alloc16(B_ * H_)};
    u16* hsb_l[2] = {alloc16(B_ * H_), alloc16(B_ * H_)};
    u16* ctx_h   = alloc16(B_ * H_);               u16* ctx_l   = alloc16(B_ * H_);

    // ---- init ----
    hipMemsetAsync(enc, 0, (size_t)B_ * S_ * H_ * sizeof(float), stream);
    hipMemsetAsync(barf, 0, 64 * sizeof(float), stream);
    hipMemsetAsync(hsf_h[0], 0, B_ * H_ * sizeof(u16), stream);
    hipMemsetAsync(hsf_l[0], 0, B_ * H_ * sizeof(u16), stream);
    hipMemsetAsync(hsb_h[0], 0, B_ * H_ * sizeof(u16), stream);
    hipMemsetAsync(hsb_l[0], 0, B_ * H_ * sizeof(u16), stream);

    // ---- embeddings (gather + split) ----
    k_embed_src_split<<<S_ * B_, 128, 0, stream>>>(src, emb, semb_h, semb_l);
    k_embed_dec_split<<<T_ * B_, 128, 0, stream>>>(src, trg, emb, demb_h, demb_l);

    // ---- weight splits ----
    k_split<<<dim3(1, H3), 256, 0, stream>>>(Wih_f, E_, E_ / 4, wihf_h, wihf_l);
    k_split<<<dim3(1, H3), 256, 0, stream>>>(Wih_b, E_, E_ / 4, wihb_h, wihb_l);
    k_split<<<dim3(1, H3), 256, 0, stream>>>(Wih_d, EH, E_ / 4, wihd_h, wihd_l);        // emb part
    k_split<<<dim3(1, H_), 256, 0, stream>>>(Wa + H_, H2, H_ / 4, wae_h, wae_l);        // enc part
    k_split<<<dim3(1, H_), 256, 0, stream>>>(Wa, H2, H_ / 4, wcat_h, wcat_l);           // hWa rows (natural)
    k_wsplit_perm<<<H3, 256, 0, stream>>>(Whh_f, H_, 0, whhf_h, whhf_l);
    k_wsplit_perm<<<H3, 256, 0, stream>>>(Whh_b, H_, 0, whhb_h, whhb_l);
    k_wsplit_perm<<<H3, 256, 0, stream>>>(Wih_d, EH, E_, wihdc_h, wihdc_l);             // ctx part, permuted
    k_wsplit_perm<<<H3, 256, 0, stream>>>(Whh_d, H_, 0, wcat_h + (size_t)1024 * H_,
                                          wcat_l + (size_t)1024 * H_);                  // ghd rows, permuted

    // ---- encoder input projections (MFMA) ----
    k_gemm_mfma3<<<dim3(16, 24), 256, 0, stream>>>(semb_h, semb_l, wihf_h, wihf_l,
                                                   bih_f, gi_f, H3, E_);
    k_gemm_mfma3<<<dim3(16, 24), 256, 0, stream>>>(semb_h, semb_l, wihb_h, wihb_l,
                                                   bih_b, gi_b, H3, E_);

    // ---- encoder: persistent, 64 steps, 1 grid-barrier each ----
    k_enc_persist<<<128, 256, 0, stream>>>(
        whhf_h, whhf_l, whhb_h, whhb_l, gi_f, gi_b, bhh_f, bhh_b,
        hsf_h[0], hsf_l[0], hsf_h[1], hsf_l[1],
        hsb_h[0], hsb_l[0], hsb_h[1], hsb_l[1],
        enc, bar_enc);

    // ---- attention precompute ep + decoder emb projection ----
    k_split<<<dim3(1, B_ * S_), 256, 0, stream>>>(enc, H_, H_ / 4, enc_h, enc_l);
    k_gemm_mfma3<<<dim3(16, 8), 256, 0, stream>>>(enc_h, enc_l, wae_h, wae_l,
                                                  ba, ep, H_, H_);
    k_gemm_mfma3<<<dim3(16, 24), 256, 0, stream>>>(demb_h, demb_l, wihd_h, wihd_l,
                                                   bih_d, gi_e, H3, E_);

    // ---- decoder: persistent, 64 steps x {P1, attn, P3}, 3 grid-barriers each ----
    k_dec_persist<<<224, 256, 0, stream>>>(
        wcat_h, wcat_l, wihdc_h, wihdc_l, gi_e, bhh_d, ep, vv, enc,
        hsf_h[0], hsf_l[0], ctx_h, ctx_l, outv, states, bar_dec);

    // ---- output head: out = states @ Wout^T + bout, 5 passes of 6400 vocab rows ----
    k_split<<<dim3(2, T_ * B_), 256, 0, stream>>>(states, H2, H2 / 4, st_h, st_l);
    for (int p = 0; p < 5; ++p) {
        k_split<<<dim3(2, 6400), 256, 0, stream>>>(Wout + (size_t)p * 6400 * H2, H2,
                                                   H2 / 4, wout_h, wout_l);
        k_gemm_mfma3<<<dim3(16, 50), 256, 0, stream>>>(st_h, st_l, wout_h, wout_l,
                                                       bout + p * 6400,
                                                       out + (size_t)p * 6400, V_, H2);
    }
}

// Round 6
// 6906.945 us; speedup vs baseline: 2.0025x; 1.0084x over previous
//
#include <hip/hip_runtime.h>
#include <hip/hip_bf16.h>

#define S_ 64
#define T_ 64
#define B_ 32
#define E_ 512
#define H_ 1024
#define V_ 32000
#define H3 3072
#define H2 2048
#define EH 1536

typedef unsigned short u16;
typedef unsigned int u32;
typedef __attribute__((ext_vector_type(8))) short bf16x8;
typedef __attribute__((ext_vector_type(4))) float f32x4;

#define MFMA3(ACC, AH_, AL_, BH_, BL_)                                              \
    ACC = __builtin_amdgcn_mfma_f32_16x16x32_bf16(AL_, BH_, ACC, 0, 0, 0);          \
    ACC = __builtin_amdgcn_mfma_f32_16x16x32_bf16(AH_, BL_, ACC, 0, 0, 0);          \
    ACC = __builtin_amdgcn_mfma_f32_16x16x32_bf16(AH_, BH_, ACC, 0, 0, 0);

__device__ __forceinline__ void splitf(float x, u16& h, u16& l) {
    u32 xb = __float_as_uint(x);
    u32 hb = (xb + 0x7FFFu + ((xb >> 16) & 1u)) & 0xFFFF0000u;  // RNE bf16 (as f32 bits)
    h = (u16)(hb >> 16);
    float lf = x - __uint_as_float(hb);                          // exact residual
    u32 lb = __float_as_uint(lf);
    l = (u16)((lb + 0x7FFFu + ((lb >> 16) & 1u)) >> 16);
}

__device__ __forceinline__ float bf2f(u16 v) { return __uint_as_float(((u32)v) << 16); }

__device__ __forceinline__ void load_lds16(const void* g, void* l) {
    __builtin_amdgcn_global_load_lds((const __attribute__((address_space(1))) u32*)g,
                                     (__attribute__((address_space(3))) u32*)l, 16, 0, 0);
}

// Hierarchical grid barrier (R5 post-mortem: single-line contention was ~15-20us/bar).
// Arrive: fetch_add on cnt[blk&7] (8 lines). Block 0 polls the 8 counters, then
// broadcasts epoch to 8 flag lines. Others read-poll flag[blk&7] (<=28 pollers/line).
__device__ __forceinline__ void gbar(int* cnt, int* flag, int nblk, int blk, int& gen) {
    __syncthreads();
    if (threadIdx.x == 0) {
        gen += 1;
        __hip_atomic_fetch_add(&cnt[(blk & 7) << 5], 1, __ATOMIC_RELEASE,
                               __HIP_MEMORY_SCOPE_AGENT);
        if (blk == 0) {
            const int target = nblk * gen;
            for (;;) {
                int sum = 0;
#pragma unroll
                for (int j = 0; j < 8; ++j)
                    sum += __hip_atomic_load(&cnt[j << 5], __ATOMIC_RELAXED,
                                             __HIP_MEMORY_SCOPE_AGENT);
                if (sum >= target) break;
                __builtin_amdgcn_s_sleep(2);
            }
            __builtin_amdgcn_fence(__ATOMIC_ACQUIRE, "agent");   // transitivity
#pragma unroll
            for (int j = 0; j < 8; ++j)
                __hip_atomic_store(&flag[j << 5], gen, __ATOMIC_RELEASE,
                                   __HIP_MEMORY_SCOPE_AGENT);
        } else {
            while (__hip_atomic_load(&flag[(blk & 7) << 5], __ATOMIC_RELAXED,
                                     __HIP_MEMORY_SCOPE_AGENT) < gen)
                __builtin_amdgcn_s_sleep(2);
        }
        __builtin_amdgcn_fence(__ATOMIC_ACQUIRE, "agent");
    }
    __syncthreads();
}

// ---------------- embedding gather + split ----------------
__global__ void k_embed_src_split(const int* __restrict__ src, const float* __restrict__ emb,
                                  u16* __restrict__ hi, u16* __restrict__ lo) {
    int row = blockIdx.x;              // s*B + b
    int tok = src[row];
    int c = threadIdx.x * 4;
    float4 v = *reinterpret_cast<const float4*>(emb + (size_t)tok * E_ + c);
    ushort4 h, l;
    splitf(v.x, h.x, l.x); splitf(v.y, h.y, l.y);
    splitf(v.z, h.z, l.z); splitf(v.w, h.w, l.w);
    *reinterpret_cast<ushort4*>(hi + (size_t)row * E_ + c) = h;
    *reinterpret_cast<ushort4*>(lo + (size_t)row * E_ + c) = l;
}

__global__ void k_embed_dec_split(const int* __restrict__ src, const int* __restrict__ trg,
                                  const float* __restrict__ emb,
                                  u16* __restrict__ hi, u16* __restrict__ lo) {
    int row = blockIdx.x;              // t*B + b
    int t = row >> 5, b = row & 31;
    int tok = (t == 0) ? src[(S_ - 1) * B_ + b] : trg[(t - 1) * B_ + b];
    int c = threadIdx.x * 4;
    float4 v = *reinterpret_cast<const float4*>(emb + (size_t)tok * E_ + c);
    ushort4 h, l;
    splitf(v.x, h.x, l.x); splitf(v.y, h.y, l.y);
    splitf(v.z, h.z, l.z); splitf(v.w, h.w, l.w);
    *reinterpret_cast<ushort4*>(hi + (size_t)row * E_ + c) = h;
    *reinterpret_cast<ushort4*>(lo + (size_t)row * E_ + c) = l;
}

// ---------------- generic f32 -> bf16 hi/lo split ----------------
__global__ __launch_bounds__(256) void k_split(const float* __restrict__ in, int ld, int cols4,
                                               u16* __restrict__ hi, u16* __restrict__ lo) {
    int c4 = blockIdx.x * 256 + threadIdx.x;
    if (c4 >= cols4) return;
    size_t r = blockIdx.y;
    float4 v = *reinterpret_cast<const float4*>(in + r * ld + (size_t)c4 * 4);
    ushort4 h, l;
    splitf(v.x, h.x, l.x); splitf(v.y, h.y, l.y);
    splitf(v.z, h.z, l.z); splitf(v.w, h.w, l.w);
    size_t o = (r * cols4 + c4) * 4;
    *reinterpret_cast<ushort4*>(hi + o) = h;
    *reinterpret_cast<ushort4*>(lo + o) = l;
}

// ---------------- gate-interleaved weight split: dst row 3i+g = src row g*1024+i ----------------
__global__ void k_wsplit_perm(const float* __restrict__ src, int ld, int coff,
                              u16* __restrict__ hi, u16* __restrict__ lo) {
    int r = blockIdx.x;                // permuted row: 3i+g
    int i = r / 3, g = r - i * 3;
    const float* p = src + (size_t)(g * H_ + i) * ld + coff;
    int c = threadIdx.x * 4;
    float4 v = *reinterpret_cast<const float4*>(p + c);
    ushort4 h, l;
    splitf(v.x, h.x, l.x); splitf(v.y, h.y, l.y);
    splitf(v.z, h.z, l.z); splitf(v.w, h.w, l.w);
    *reinterpret_cast<ushort4*>(hi + (size_t)r * H_ + c) = h;
    *reinterpret_cast<ushort4*>(lo + (size_t)r * H_ + c) = l;
}

// ---------------- big split-bf16 MFMA GEMM (proven R2-R5) ----------------
__global__ __launch_bounds__(256, 2) void k_gemm_mfma3(
    const u16* __restrict__ Ah, const u16* __restrict__ Al,
    const u16* __restrict__ Bh, const u16* __restrict__ Bl,
    const float* __restrict__ bias, float* __restrict__ C,
    int ldc, int K)
{
    __shared__ u16 ls[4][128 * 32];
    const int tid = threadIdx.x;
    const int lane = tid & 63, w = tid >> 6;
    const int wr = w >> 1, wc = w & 1;
    const size_t m0 = (size_t)blockIdx.x * 128, n0 = (size_t)blockIdx.y * 128;

    const int c0 = (w * 2) * 64 + lane;
    const int r0 = c0 >> 2, kc0 = (c0 & 3) << 3;
    const size_t rstep = (size_t)16 * K;
    const u16* gAh = Ah + (m0 + r0) * K + kc0;
    const u16* gAl = Al + (m0 + r0) * K + kc0;
    const u16* gBh = Bh + (n0 + r0) * K + kc0;
    const u16* gBl = Bl + (n0 + r0) * K + kc0;
    const int lo0 = c0 * 8;

    const int frow = lane & 15, fk = (lane >> 4) << 3;
    const int offA = (wr * 64 + frow) * 32 + fk;
    const int offB = (wc * 64 + frow) * 32 + fk;

    f32x4 acc[4][4] = {};

    for (int k0 = 0; k0 < K; k0 += 32) {
        load_lds16(gAh + k0, &ls[0][lo0]);
        load_lds16(gAh + rstep + k0, &ls[0][lo0 + 512]);
        load_lds16(gAl + k0, &ls[1][lo0]);
        load_lds16(gAl + rstep + k0, &ls[1][lo0 + 512]);
        load_lds16(gBh + k0, &ls[2][lo0]);
        load_lds16(gBh + rstep + k0, &ls[2][lo0 + 512]);
        load_lds16(gBl + k0, &ls[3][lo0]);
        load_lds16(gBl + rstep + k0, &ls[3][lo0 + 512]);
        __syncthreads();

        bf16x8 fAh[4], fAl[4], fBh[4], fBl[4];
#pragma unroll
        for (int m = 0; m < 4; ++m) {
            fAh[m] = *reinterpret_cast<const bf16x8*>(&ls[0][offA + m * 512]);
            fAl[m] = *reinterpret_cast<const bf16x8*>(&ls[1][offA + m * 512]);
        }
#pragma unroll
        for (int n = 0; n < 4; ++n) {
            fBh[n] = *reinterpret_cast<const bf16x8*>(&ls[2][offB + n * 512]);
            fBl[n] = *reinterpret_cast<const bf16x8*>(&ls[3][offB + n * 512]);
        }
#pragma unroll
        for (int m = 0; m < 4; ++m)
#pragma unroll
            for (int n = 0; n < 4; ++n) {
                MFMA3(acc[m][n], fAh[m], fAl[m], fBh[n], fBl[n]);
            }
        __syncthreads();
    }

    const int crow0 = wr * 64 + ((lane >> 4) << 2);
    const int ccol0 = wc * 64 + (lane & 15);
#pragma unroll
    for (int n = 0; n < 4; ++n) {
        const size_t col = n0 + ccol0 + n * 16;
        const float bv = bias ? bias[col] : 0.f;
#pragma unroll
        for (int m = 0; m < 4; ++m)
#pragma unroll
            for (int r = 0; r < 4; ++r)
                C[(m0 + crow0 + m * 16 + r) * (size_t)ldc + col] = acc[m][n][r] + bv;
    }
}

// ================= persistent encoder: 64 GRU steps, both dirs, 1 barrier/step =================
__global__ __launch_bounds__(256) void k_enc_persist(
    const u16* __restrict__ whhf_h, const u16* __restrict__ whhf_l,
    const u16* __restrict__ whhb_h, const u16* __restrict__ whhb_l,
    const float* __restrict__ gi_f, const float* __restrict__ gi_b,
    const float* __restrict__ bhh_f, const float* __restrict__ bhh_b,
    u16* __restrict__ hfH0, u16* __restrict__ hfL0,
    u16* __restrict__ hfH1, u16* __restrict__ hfL1,
    u16* __restrict__ hbH0, u16* __restrict__ hbL0,
    u16* __restrict__ hbH1, u16* __restrict__ hbL1,
    float* __restrict__ enc, int* __restrict__ cnt, int* __restrict__ flag)
{
    __shared__ __align__(16) char smem[107008];
    u16* lH = (u16*)smem;                       // [48][1024] hi weights, XOR-swizzled
    float* ex = (float*)(smem + 98304);         // [48][33] gh exchange
    float* hloc = (float*)(smem + 104704);      // [32][16] f32 state

    const int blk = blockIdx.x, tid = threadIdx.x;
    const int lane = tid & 63, w = tid >> 6;
    const int dir = blk >> 6, c = blk & 63;
    const int i0 = c * 16;
    const size_t rowbase = (size_t)c * 48;
    const u16* WH = (dir ? whhb_h : whhf_h) + rowbase * 1024;
    const u16* WL = (dir ? whhb_l : whhf_l) + rowbase * 1024;
    const float* gi = dir ? gi_b : gi_f;
    const float* bhh = dir ? bhh_b : bhh_f;
    int gen = 0;

    for (int ch = tid; ch < 6144; ch += 256) {   // 48 rows x 128 chunks
        int r = ch >> 7, kc = (ch & 127) << 3;
        *(bf16x8*)&lH[r * 1024 + (kc ^ ((r & 7) << 3))] =
            *(const bf16x8*)&WH[(size_t)r * 1024 + kc];
    }
    for (int q = tid; q < 512; q += 256) hloc[q] = 0.f;
    __syncthreads();

    const int frow = lane & 15, fk8 = (lane >> 4) << 3;
    const int cb = lane & 15, rb0 = (lane >> 4) << 2;

    for (int t = 0; t < 64; ++t) {
        const int a = t & 1;
        const u16* rH = dir ? (a ? hbH1 : hbH0) : (a ? hfH1 : hfH0);
        const u16* rL = dir ? (a ? hbL1 : hbL0) : (a ? hfL1 : hfL0);
        u16* oH = dir ? (a ? hbH0 : hbH1) : (a ? hfH0 : hfH1);
        u16* oL = dir ? (a ? hbL0 : hbL1) : (a ? hfL0 : hfL1);
        const int s = dir ? 63 - t : t;

        if (w < 2) {                              // tiles (m0,n=w),(m1,n=w)
            f32x4 acc0 = {}, acc1 = {};
            const int lrB = w * 16 + frow;
            const int bsw = (lrB & 7) << 3;
            const u16* gBl = WL + (size_t)lrB * 1024;
#pragma unroll 4
            for (int k0 = 0; k0 < 1024; k0 += 32) {
                int kc = k0 + fk8;
                bf16x8 bH = *(const bf16x8*)&lH[lrB * 1024 + (kc ^ bsw)];
                bf16x8 bL = *(const bf16x8*)&gBl[kc];
                bf16x8 aH0 = *(const bf16x8*)&rH[frow * 1024 + kc];
                bf16x8 aL0 = *(const bf16x8*)&rL[frow * 1024 + kc];
                bf16x8 aH1 = *(const bf16x8*)&rH[(16 + frow) * 1024 + kc];
                bf16x8 aL1 = *(const bf16x8*)&rL[(16 + frow) * 1024 + kc];
                MFMA3(acc0, aH0, aL0, bH, bL);
                MFMA3(acc1, aH1, aL1, bH, bL);
            }
            int pc = w * 16 + cb;
#pragma unroll
            for (int r = 0; r < 4; ++r) {
                ex[pc * 33 + rb0 + r] = acc0[r];
                ex[pc * 33 + 16 + rb0 + r] = acc1[r];
            }
        } else {                                  // single tile (m=w-2, n=2), k-parity dual acc
            f32x4 acc0 = {}, acc1 = {};
            const int m = w - 2;
            const int lrB = 32 + frow;
            const int bsw = (lrB & 7) << 3;
            const u16* gBl = WL + (size_t)lrB * 1024;
#pragma unroll 2
            for (int k0 = 0; k0 < 1024; k0 += 64) {
                {
                    int kc = k0 + fk8;
                    bf16x8 bH = *(const bf16x8*)&lH[lrB * 1024 + (kc ^ bsw)];
                    bf16x8 bL = *(const bf16x8*)&gBl[kc];
                    bf16x8 aH = *(const bf16x8*)&rH[(m * 16 + frow) * 1024 + kc];
                    bf16x8 aL = *(const bf16x8*)&rL[(m * 16 + frow) * 1024 + kc];
                    MFMA3(acc0, aH, aL, bH, bL);
                }
                {
                    int kc = k0 + 32 + fk8;
                    bf16x8 bH = *(const bf16x8*)&lH[lrB * 1024 + (kc ^ bsw)];
                    bf16x8 bL = *(const bf16x8*)&gBl[kc];
                    bf16x8 aH = *(const bf16x8*)&rH[(m * 16 + frow) * 1024 + kc];
                    bf16x8 aL = *(const bf16x8*)&rL[(m * 16 + frow) * 1024 + kc];
                    MFMA3(acc1, aH, aL, bH, bL);
                }
            }
            f32x4 accs = acc0 + acc1;
            int pc = 32 + cb;
#pragma unroll
            for (int r = 0; r < 4; ++r)
                ex[pc * 33 + m * 16 + rb0 + r] = accs[r];
        }
        __syncthreads();

        {   // gate fusion
            const int il = tid & 15, bb = tid >> 4;
            const int i = i0 + il;
#pragma unroll
            for (int q = 0; q < 2; ++q) {
                int b = bb + q * 16;
                float ghr = ex[(3 * il + 0) * 33 + b] + bhh[i];
                float ghz = ex[(3 * il + 1) * 33 + b] + bhh[H_ + i];
                float ghn = ex[(3 * il + 2) * 33 + b] + bhh[2 * H_ + i];
                size_t gio = (size_t)(s * B_ + b) * H3 + i;
                float gir = gi[gio], giz = gi[gio + H_], gin = gi[gio + 2 * H_];
                float rr = 1.f / (1.f + expf(-(gir + ghr)));
                float zz = 1.f / (1.f + expf(-(giz + ghz)));
                float nn = tanhf(gin + rr * ghn);
                float hold = hloc[b * 16 + il];
                float hnew = (1.f - zz) * nn + zz * hold;
                hloc[b * 16 + il] = hnew;
                u16 hh, hl; splitf(hnew, hh, hl);
                oH[b * 1024 + i] = hh;
                oL[b * 1024 + i] = hl;
                enc[((size_t)b * 64 + s) * H_ + i] += hnew;
            }
        }
        gbar(cnt, flag, 128, blk, gen);
    }
}

// ================= persistent decoder: 64 steps, 4 uniform phases, 4 barriers/step =================
// grid 256. Each block: pins 16 wcat rows (Ph1), 8 score-pairs (Ph2),
// (b=blk>>3, sl=blk&7) 512-col weighted-sum slice (Ph3), 128 gate units (Ph4).
__global__ __launch_bounds__(256) void k_dec_persist(
    const u16* __restrict__ wcat_h, const u16* __restrict__ wcat_l,
    const float* __restrict__ gi_e, const float* __restrict__ bhh_d,
    const float* __restrict__ ep, const float* __restrict__ vvec,
    const float* __restrict__ enc, const float* __restrict__ encW,
    u16* __restrict__ hH, u16* __restrict__ hL, float* __restrict__ hf32,
    float* __restrict__ outv, float* __restrict__ scores,
    float* __restrict__ gicv, float* __restrict__ states,
    int* __restrict__ cnt, int* __restrict__ flag)
{
    __shared__ __align__(16) char smem[66048];
    u16* lwH = (u16*)smem;                      // [16][1024] swizzled
    u16* lwL = (u16*)(smem + 32768);
    float* al_s = (float*)(smem + 65536);       // [64]
    float* aw_s = (float*)(smem + 65792);       // [64]

    const int blk = blockIdx.x, tid = threadIdx.x;
    const int lane = tid & 63, w = tid >> 6;
    const int frow = lane & 15, fk8 = (lane >> 4) << 3;
    const int b3 = blk >> 3, sl = blk & 7;
    int gen = 0;

    {   // pin 16 wcat rows in LDS (hi+lo), XOR-swizzled
        const u16* gH = wcat_h + (size_t)blk * 16 * 1024;
        const u16* gL = wcat_l + (size_t)blk * 16 * 1024;
        for (int ch = tid; ch < 2048; ch += 256) {
            int r = ch >> 7, kc = (ch & 127) << 3;
            int sw = kc ^ ((r & 7) << 3);
            *(bf16x8*)&lwH[r * 1024 + sw] = *(const bf16x8*)&gH[(size_t)r * 1024 + kc];
            *(bf16x8*)&lwL[r * 1024 + sw] = *(const bf16x8*)&gL[(size_t)r * 1024 + kc];
        }
    }
    __syncthreads();

    for (int t = 0; t < 64; ++t) {
        // ---- Ph1: outv[:, 16blk..16blk+16) = h @ wcatrows^T (waves 0,1; m=w) ----
        if (w < 2) {
            f32x4 acc0 = {}, acc1 = {};
            const int bsw = (frow & 7) << 3;
            const int ar0 = (w * 16 + frow) * 1024;
#pragma unroll 2
            for (int k0 = 0; k0 < 1024; k0 += 64) {
                {
                    int kc = k0 + fk8;
                    bf16x8 aH = *(const bf16x8*)&hH[ar0 + kc];
                    bf16x8 aL = *(const bf16x8*)&hL[ar0 + kc];
                    bf16x8 bH = *(const bf16x8*)&lwH[frow * 1024 + (kc ^ bsw)];
                    bf16x8 bL = *(const bf16x8*)&lwL[frow * 1024 + (kc ^ bsw)];
                    MFMA3(acc0, aH, aL, bH, bL);
                }
                {
                    int kc = k0 + 32 + fk8;
                    bf16x8 aH = *(const bf16x8*)&hH[ar0 + kc];
                    bf16x8 aL = *(const bf16x8*)&hL[ar0 + kc];
                    bf16x8 bH = *(const bf16x8*)&lwH[frow * 1024 + (kc ^ bsw)];
                    bf16x8 bL = *(const bf16x8*)&lwL[frow * 1024 + (kc ^ bsw)];
                    MFMA3(acc1, aH, aL, bH, bL);
                }
            }
            f32x4 acc = acc0 + acc1;
            const int col = blk * 16 + frow;
            const int b0 = w * 16 + ((lane >> 4) << 2);
#pragma unroll
            for (int r = 0; r < 4; ++r)
                outv[(size_t)(b0 + r) * 4096 + col] = acc[r];
        }
        gbar(cnt, flag, 256, blk, gen);

        // ---- Ph2: scores, 8 (b,s) pairs per block ----
#pragma unroll
        for (int q = 0; q < 2; ++q) {
            int p = blk * 8 + w * 2 + q;
            int b = p >> 6, s = p & 63;
            const float* epr = ep + ((size_t)b * 64 + s) * 1024;
            const float* hv = outv + (size_t)b * 4096;
            float a2 = 0.f;
#pragma unroll 4
            for (int i = 0; i < 16; ++i) {
                int j = lane + i * 64;
                a2 += fmaxf(hv[j] + epr[j], 0.f) * vvec[j];
            }
            for (int off = 32; off; off >>= 1) a2 += __shfl_down(a2, off);
            if (lane == 0) scores[p] = a2;
        }
        gbar(cnt, flag, 256, blk, gen);

        // ---- Ph3: softmax + weighted 512-col slice of [ctx | encW] ----
        if (tid < 64) al_s[tid] = scores[b3 * 64 + tid];
        __syncthreads();
        if (tid < 64) {
            float sc = al_s[tid];
            float m = sc;
            for (int off = 32; off; off >>= 1) m = fmaxf(m, __shfl_xor(m, off));
            float e = expf(sc - m);
            float sum = e;
            for (int off = 32; off; off >>= 1) sum += __shfl_xor(sum, off);
            aw_s[tid] = e / sum;
        }
        __syncthreads();
        {
            const float* src;
            int ld;
            if (sl < 2) { src = enc + (size_t)b3 * 64 * 1024 + sl * 512; ld = 1024; }
            else        { src = encW + (size_t)b3 * 64 * 3072 + (sl - 2) * 512; ld = 3072; }
            const int c2 = tid * 2;
            float ax = 0.f, ay = 0.f;
#pragma unroll 4
            for (int s2 = 0; s2 < 64; ++s2) {
                float a = aw_s[s2];
                float2 v2 = *(const float2*)&src[(size_t)s2 * ld + c2];
                ax += a * v2.x; ay += a * v2.y;
            }
            float2 o2; o2.x = ax; o2.y = ay;
            if (sl < 2)
                *(float2*)&states[((size_t)t * 32 + b3) * 2048 + 1024 + sl * 512 + c2] = o2;
            else
                *(float2*)&gicv[b3 * 3072 + (sl - 2) * 512 + c2] = o2;
        }
        gbar(cnt, flag, 256, blk, gen);

        // ---- Ph4: GRU gates for 128 units ----
        if (tid < 128) {
            int u = sl * 128 + tid;
            size_t ge = ((size_t)t * 32 + b3) * 3072;
            float gir = gi_e[ge + u]        + gicv[b3 * 3072 + u];
            float giz = gi_e[ge + 1024 + u] + gicv[b3 * 3072 + 1024 + u];
            float gin = gi_e[ge + 2048 + u] + gicv[b3 * 3072 + 2048 + u];
            size_t gv = (size_t)b3 * 4096 + 1024 + 3 * (size_t)u;
            float ghr = outv[gv + 0] + bhh_d[u];
            float ghz = outv[gv + 1] + bhh_d[1024 + u];
            float ghn = outv[gv + 2] + bhh_d[2048 + u];
            float rr = 1.f / (1.f + expf(-(gir + ghr)));
            float zz = 1.f / (1.f + expf(-(giz + ghz)));
            float nn = tanhf(gin + rr * ghn);
            float hold = t ? hf32[b3 * 1024 + u]
                           : (bf2f(hH[b3 * 1024 + u]) + bf2f(hL[b3 * 1024 + u]));
            float hnew = (1.f - zz) * nn + zz * hold;
            hf32[b3 * 1024 + u] = hnew;
            u16 hh, hl; splitf(hnew, hh, hl);
            hH[b3 * 1024 + u] = hh;
            hL[b3 * 1024 + u] = hl;
            states[((size_t)t * 32 + b3) * 2048 + u] = hnew;
        }
        gbar(cnt, flag, 256, blk, gen);
    }
}

extern "C" void kernel_launch(void* const* d_in, const int* in_sizes, int n_in,
                              void* d_out, int out_size, void* d_ws, size_t ws_size,
                              hipStream_t stream) {
    const int*   src   = (const int*)d_in[0];
    const int*   trg   = (const int*)d_in[1];
    const float* emb   = (const float*)d_in[2];
    const float* Wih_f = (const float*)d_in[3];
    const float* Whh_f = (const float*)d_in[4];
    const float* bih_f = (const float*)d_in[5];
    const float* bhh_f = (const float*)d_in[6];
    const float* Wih_b = (const float*)d_in[7];
    const float* Whh_b = (const float*)d_in[8];
    const float* bih_b = (const float*)d_in[9];
    const float* bhh_b = (const float*)d_in[10];
    const float* Wa    = (const float*)d_in[11];
    const float* ba    = (const float*)d_in[12];
    const float* vv    = (const float*)d_in[13];
    const float* Wih_d = (const float*)d_in[14];
    const float* Whh_d = (const float*)d_in[15];
    const float* bih_d = (const float*)d_in[16];
    const float* bhh_d = (const float*)d_in[17];
    const float* Wout  = (const float*)d_in[18];
    const float* bout  = (const float*)d_in[19];
    float* out = (float*)d_out;
    (void)in_sizes; (void)n_in; (void)out_size; (void)ws_size;

    float* w = (float*)d_ws;
    size_t o = 0;
    auto alloc = [&](size_t n) { float* p = w + o; o += n; return p; };
    float* gi_f  = alloc((size_t)S_ * B_ * H3);      // encoder fwd gi; reused as gi_e
    float* gi_b  = alloc((size_t)S_ * B_ * H3);      // encoder bwd gi; reused as states
    float* enc   = alloc((size_t)B_ * S_ * H_);
    float* ep    = alloc((size_t)B_ * S_ * H_);
    float* encW  = alloc((size_t)B_ * S_ * H3);      // enc @ Wihd_ctx^T (natural layout)
    float* outv  = alloc((size_t)B_ * 4096);
    float* gicv  = alloc((size_t)B_ * H3);
    float* hf32  = alloc((size_t)B_ * H_);
    float* scores = alloc(B_ * S_);
    float* barf  = alloc(1024);                       // 4 x 8-line barrier arrays
    int* cntE  = (int*)barf;
    int* flagE = cntE + 256;
    int* cntD  = cntE + 512;
    int* flagD = cntE + 768;
    float* gi_e   = gi_f;
    float* states = gi_b;

    u16* wu = (u16*)(w + o);
    size_t ou = 0;
    auto alloc16 = [&](size_t n) { u16* p = wu + ou; ou += n; return p; };
    u16* semb_h  = alloc16((size_t)S_ * B_ * E_);  u16* semb_l  = alloc16((size_t)S_ * B_ * E_);
    u16* demb_h  = alloc16((size_t)T_ * B_ * E_);  u16* demb_l  = alloc16((size_t)T_ * B_ * E_);
    u16* wihf_h  = alloc16((size_t)H3 * E_);       u16* wihf_l  = alloc16((size_t)H3 * E_);
    u16* wihb_h  = alloc16((size_t)H3 * E_);       u16* wihb_l  = alloc16((size_t)H3 * E_);
    u16* wihd_h  = alloc16((size_t)H3 * E_);       u16* wihd_l  = alloc16((size_t)H3 * E_);
    u16* wae_h   = alloc16((size_t)H_ * H_);       u16* wae_l   = alloc16((size_t)H_ * H_);
    u16* enc_h   = alloc16((size_t)B_ * S_ * H_);  u16* enc_l   = alloc16((size_t)B_ * S_ * H_);
    u16* st_h    = alloc16((size_t)T_ * B_ * H2);  u16* st_l    = alloc16((size_t)T_ * B_ * H2);
    u16* wout_h  = alloc16((size_t)6400 * H2);     u16* wout_l  = alloc16((size_t)6400 * H2);
    u16* whhf_h  = alloc16((size_t)H3 * H_);       u16* whhf_l  = alloc16((size_t)H3 * H_);   // permuted
    u16* whhb_h  = alloc16((size_t)H3 * H_);       u16* whhb_l  = alloc16((size_t)H3 * H_);   // permuted
    u16* wdcn_h  = alloc16((size_t)H3 * H_);       u16* wdcn_l  = alloc16((size_t)H3 * H_);   // ctx part, NATURAL
    u16* wcat_h  = alloc16((size_t)4096 * H_);     u16* wcat_l  = alloc16((size_t)4096 * H_); // natural+perm
    u16* hsf_h[2] = {alloc16(B_ * H_), alloc16(B_ * H_)};
    u16* hsf_l[2] = {alloc16(B_ * H_), alloc16(B_ * H_)};
    u16* hsb_h[2] = {alloc16(B_ * H_), alloc16(B_ * H_)};
    u16* hsb_l[2] = {alloc16(B_ * H_), alloc16(B_ * H_)};

    // ---- init ----
    hipMemsetAsync(enc, 0, (size_t)B_ * S_ * H_ * sizeof(float), stream);
    hipMemsetAsync(barf, 0, 1024 * sizeof(float), stream);
    hipMemsetAsync(hsf_h[0], 0, B_ * H_ * sizeof(u16), stream);
    hipMemsetAsync(hsf_l[0], 0, B_ * H_ * sizeof(u16), stream);
    hipMemsetAsync(hsb_h[0], 0, B_ * H_ * sizeof(u16), stream);
    hipMemsetAsync(hsb_l[0], 0, B_ * H_ * sizeof(u16), stream);

    // ---- embeddings (gather + split) ----
    k_embed_src_split<<<S_ * B_, 128, 0, stream>>>(src, emb, semb_h, semb_l);
    k_embed_dec_split<<<T_ * B_, 128, 0, stream>>>(src, trg, emb, demb_h, demb_l);

    // ---- weight splits ----
    k_split<<<dim3(1, H3), 256, 0, stream>>>(Wih_f, E_, E_ / 4, wihf_h, wihf_l);
    k_split<<<dim3(1, H3), 256, 0, stream>>>(Wih_b, E_, E_ / 4, wihb_h, wihb_l);
    k_split<<<dim3(1, H3), 256, 0, stream>>>(Wih_d, EH, E_ / 4, wihd_h, wihd_l);        // emb part
    k_split<<<dim3(1, H3), 256, 0, stream>>>(Wih_d + E_, EH, H_ / 4, wdcn_h, wdcn_l);   // ctx part, natural
    k_split<<<dim3(1, H_), 256, 0, stream>>>(Wa + H_, H2, H_ / 4, wae_h, wae_l);        // enc part
    k_split<<<dim3(1, H_), 256, 0, stream>>>(Wa, H2, H_ / 4, wcat_h, wcat_l);           // hWa rows (natural)
    k_wsplit_perm<<<H3, 256, 0, stream>>>(Whh_f, H_, 0, whhf_h, whhf_l);
    k_wsplit_perm<<<H3, 256, 0, stream>>>(Whh_b, H_, 0, whhb_h, whhb_l);
    k_wsplit_perm<<<H3, 256, 0, stream>>>(Whh_d, H_, 0, wcat_h + (size_t)1024 * H_,
                                          wcat_l + (size_t)1024 * H_);                  // ghd rows, permuted

    // ---- encoder input projections (MFMA) ----
    k_gemm_mfma3<<<dim3(16, 24), 256, 0, stream>>>(semb_h, semb_l, wihf_h, wihf_l,
                                                   bih_f, gi_f, H3, E_);
    k_gemm_mfma3<<<dim3(16, 24), 256, 0, stream>>>(semb_h, semb_l, wihb_h, wihb_l,
                                                   bih_b, gi_b, H3, E_);

    // ---- encoder: persistent, 64 steps, 1 grid-barrier each ----
    k_enc_persist<<<128, 256, 0, stream>>>(
        whhf_h, whhf_l, whhb_h, whhb_l, gi_f, gi_b, bhh_f, bhh_b,
        hsf_h[0], hsf_l[0], hsf_h[1], hsf_l[1],
        hsb_h[0], hsb_l[0], hsb_h[1], hsb_l[1],
        enc, cntE, flagE);

    // ---- attention precompute ep + encW + decoder emb projection ----
    k_split<<<dim3(1, B_ * S_), 256, 0, stream>>>(enc, H_, H_ / 4, enc_h, enc_l);
    k_gemm_mfma3<<<dim3(16, 8), 256, 0, stream>>>(enc_h, enc_l, wae_h, wae_l,
                                                  ba, ep, H_, H_);
    k_gemm_mfma3<<<dim3(16, 24), 256, 0, stream>>>(enc_h, enc_l, wdcn_h, wdcn_l,
                                                   nullptr, encW, H3, H_);
    k_gemm_mfma3<<<dim3(16, 24), 256, 0, stream>>>(demb_h, demb_l, wihd_h, wihd_l,
                                                   bih_d, gi_e, H3, E_);

    // ---- decoder: persistent, 64 steps x 4 uniform phases ----
    k_dec_persist<<<256, 256, 0, stream>>>(
        wcat_h, wcat_l, gi_e, bhh_d, ep, vv, enc, encW,
        hsf_h[0], hsf_l[0], hf32, outv, scores, gicv, states, cntD, flagD);

    // ---- output head: out = states @ Wout^T + bout, 5 passes of 6400 vocab rows ----
    k_split<<<dim3(2, T_ * B_), 256, 0, stream>>>(states, H2, H2 / 4, st_h, st_l);
    for (int p = 0; p < 5; ++p) {
        k_split<<<dim3(2, 6400), 256, 0, stream>>>(Wout + (size_t)p * 6400 * H2, H2,
                                                   H2 / 4, wout_h, wout_l);
        k_gemm_mfma3<<<dim3(16, 50), 256, 0, stream>>>(st_h, st_l, wout_h, wout_l,
                                                       bout + p * 6400,
                                                       out + (size_t)p * 6400, V_, H2);
    }
}